// Round 7
// baseline (1869.747 us; speedup 1.0000x reference)
//
#include <hip/hip_runtime.h>
#include <math.h>

// ---------------- constants ----------------
static constexpr int kB = 128;
static constexpr int kT = 50;

// ---------- packed transpose [N][O][C] -> [N][C][O], 9 segments, one launch ----------
struct TDesc { const float* src; float* dst; int O; int C; int total; };
struct TPack { TDesc d[9]; };
__global__ void k_transpose_pack(TPack p) {
    TDesc t = p.d[blockIdx.y];
    int idx = blockIdx.x * 256 + threadIdx.x;
    if (idx >= t.total) return;
    int o = idx % t.O; int r = idx / t.O; int c = r % t.C; int n = r / t.C;
    t.dst[idx] = t.src[((size_t)n * t.O + o) * t.C + c];
}

// ---------- fused stem: conv1{a,b,b} + BN + ReLU + bilinear resize + concat ----------
__global__ void k_stem(const float* __restrict__ mt, const float* __restrict__ mf,
                       const float* __restrict__ mc,
                       const float* __restrict__ w1a, const float* __restrict__ b1a,
                       const float* __restrict__ g1a, const float* __restrict__ be1a,
                       const float* __restrict__ m1a, const float* __restrict__ v1a,
                       const float* __restrict__ w1b, const float* __restrict__ b1b,
                       const float* __restrict__ g1b, const float* __restrict__ be1b,
                       const float* __restrict__ m1b, const float* __restrict__ v1b,
                       float* __restrict__ out, int total) {
    int idx = blockIdx.x * blockDim.x + threadIdx.x;
    if (idx >= total) return;
    int ox = idx % 156; int t = idx / 156;
    int oy = t % 25; t /= 25;
    int ch = t % 24; int b = t / 24;
    int grp = ch >> 3, c = ch & 7;
    const float* src; int Hc, Wc;
    const float *wb, *cb, *g, *be, *m, *v;
    if (grp == 0) { src = mt; Hc = 196; Wc = 39; wb = w1a + c * 10;
                    cb = b1a; g = g1a; be = be1a; m = m1a; v = v1a; }
    else          { src = (grp == 1 ? mf : mc); Hc = 199; Wc = 35; wb = w1b + c * 12;
                    cb = b1b; g = g1b; be = be1b; m = m1b; v = v1b; }
    float s = g[c] * rsqrtf(v[c] + 1e-5f);
    float bias = (cb[c] - m[c]) * s + be[c];
    float sy = (oy + 0.5f) * ((float)Hc / 25.f) - 0.5f;
    float sx = (ox + 0.5f) * ((float)Wc / 156.f) - 0.5f;
    float fy0 = floorf(sy), fx0 = floorf(sx);
    float fy = sy - fy0, fx = sx - fx0;
    int y0 = (int)fy0, x0 = (int)fx0;
    int y0c = min(max(y0, 0), Hc - 1), y1c = min(max(y0 + 1, 0), Hc - 1);
    int x0c = min(max(x0, 0), Wc - 1), x1c = min(max(x0 + 1, 0), Wc - 1);
    const float* p = src + (size_t)b * 8000;   // 200*40
    float t00 = 0.f, t01 = 0.f, t10 = 0.f, t11 = 0.f;
    if (grp == 0) {
        #pragma unroll
        for (int ky = 0; ky < 5; ++ky)
            #pragma unroll
            for (int kx = 0; kx < 2; ++kx) {
                float wv = wb[ky * 2 + kx];
                t00 += p[(y0c + ky) * 40 + x0c + kx] * wv;
                t01 += p[(y0c + ky) * 40 + x1c + kx] * wv;
                t10 += p[(y1c + ky) * 40 + x0c + kx] * wv;
                t11 += p[(y1c + ky) * 40 + x1c + kx] * wv;
            }
    } else {
        #pragma unroll
        for (int ky = 0; ky < 2; ++ky)
            #pragma unroll
            for (int kx = 0; kx < 6; ++kx) {
                float wv = wb[ky * 6 + kx];
                t00 += p[(y0c + ky) * 40 + x0c + kx] * wv;
                t01 += p[(y0c + ky) * 40 + x1c + kx] * wv;
                t10 += p[(y1c + ky) * 40 + x0c + kx] * wv;
                t11 += p[(y1c + ky) * 40 + x1c + kx] * wv;
            }
    }
    float r00 = fmaxf(t00 * s + bias, 0.f), r01 = fmaxf(t01 * s + bias, 0.f);
    float r10 = fmaxf(t10 * s + bias, 0.f), r11 = fmaxf(t11 * s + bias, 0.f);
    out[idx] = r00 * (1.f - fy) * (1.f - fx) + r01 * (1.f - fy) * fx
             + r10 * fy * (1.f - fx) + r11 * fy * fx;
}

// ---------- LDS-tiled 3x3 conv, pad 1, fused BN(eval) + ReLU ----------
template<int CIN, int CI_T, int H, int W, int ROWS, int NPX>
__global__ void __launch_bounds__(256) k_conv3x3_tiled(
    const float* __restrict__ in, const float* __restrict__ wT,
    const float* __restrict__ cb, const float* __restrict__ g,
    const float* __restrict__ be, const float* __restrict__ m,
    const float* __restrict__ v, float* __restrict__ out, int COUT) {
    constexpr int WP = W + 2;
    constexpr int RP = ROWS + 2;
    constexpr int STAGE = CI_T * RP * WP;
    __shared__ float sx[STAGE];
    __shared__ float sw[CI_T * 9 * 8];
    const int b = blockIdx.x, rt = blockIdx.y, oc0 = blockIdx.z * 8;
    const int row0 = rt * ROWS;
    const int tid = threadIdx.x;

    int off[NPX]; bool val[NPX];
    #pragma unroll
    for (int j = 0; j < NPX; ++j) {
        int px = tid + j * 256;
        int oy = px / W, ox = px - oy * W;
        bool ok = (px < ROWS * W) && (row0 + oy < H);
        val[j] = ok;
        off[j] = ok ? (oy * WP + ox) : 0;
    }

    float acc[NPX][8];
    #pragma unroll
    for (int j = 0; j < NPX; ++j)
        #pragma unroll
        for (int o = 0; o < 8; ++o) acc[j][o] = 0.f;

    for (int c0 = 0; c0 < CIN; c0 += CI_T) {
        __syncthreads();
        for (int e = tid; e < STAGE; e += 256) {
            int ci = e / (RP * WP);
            int rem = e - ci * RP * WP;
            int r = rem / WP;
            int xx = rem - r * WP;
            int iy = row0 - 1 + r;
            int ix = xx - 1;
            float vv = 0.f;
            if (iy >= 0 && iy < H && ix >= 0 && ix < W)
                vv = in[((size_t)(b * CIN + c0 + ci) * H + iy) * W + ix];
            sx[e] = vv;
        }
        for (int e = tid; e < CI_T * 9 * 8; e += 256) {
            int rk = e >> 3;
            int o = e & 7;
            sw[e] = wT[((size_t)c0 * 9 + rk) * COUT + oc0 + o];
        }
        __syncthreads();
        #pragma unroll 1
        for (int cl = 0; cl < CI_T; ++cl) {
            const float* sxc = sx + cl * RP * WP;
            #pragma unroll
            for (int k = 0; k < 9; ++k) {
                const int ky = k / 3, kx = k % 3;
                const float4 wa = *(const float4*)(sw + (cl * 9 + k) * 8);
                const float4 wb = *(const float4*)(sw + (cl * 9 + k) * 8 + 4);
                #pragma unroll
                for (int j = 0; j < NPX; ++j) {
                    float xv = sxc[off[j] + ky * WP + kx];
                    acc[j][0] += xv * wa.x; acc[j][1] += xv * wa.y;
                    acc[j][2] += xv * wa.z; acc[j][3] += xv * wa.w;
                    acc[j][4] += xv * wb.x; acc[j][5] += xv * wb.y;
                    acc[j][6] += xv * wb.z; acc[j][7] += xv * wb.w;
                }
            }
        }
    }
    float sc[8], bi[8];
    #pragma unroll
    for (int o = 0; o < 8; ++o) {
        float s = g[oc0 + o] * rsqrtf(v[oc0 + o] + 1e-5f);
        sc[o] = s; bi[o] = (cb[oc0 + o] - m[oc0 + o]) * s + be[oc0 + o];
    }
    #pragma unroll
    for (int j = 0; j < NPX; ++j) if (val[j]) {
        int px = tid + j * 256;
        int oy = row0 + px / W, ox = px % W;
        #pragma unroll
        for (int o = 0; o < 8; ++o)
            out[((size_t)(b * COUT + oc0 + o) * H + oy) * W + ox] =
                fmaxf(acc[j][o] * sc[o] + bi[o], 0.f);
    }
}

// ---------- 2x2 maxpool stride 2 (VALID) ----------
__global__ void k_maxpool(const float* __restrict__ in, float* __restrict__ out,
                          int C, int Hin, int Win, int Hout, int Wout, int total) {
    int idx = blockIdx.x * blockDim.x + threadIdx.x;
    if (idx >= total) return;
    int ox = idx % Wout; int t = idx / Wout;
    int oy = t % Hout; t /= Hout;
    int c = t % C; int b = t / C;
    const float* p = in + ((size_t)(b * C + c) * Hin + 2 * oy) * Win + 2 * ox;
    float m0 = fmaxf(p[0], p[1]);
    float m1 = fmaxf(p[Win], p[Win + 1]);
    out[idx] = fmaxf(m0, m1);
}

// ---------- fused audio attention (both stages) + spatial GAP ----------
// TILE_P=13 (18 tiles x 13 = 234): halves the accumulator arrays (VGPR ~64)
// and LDS (~13 KB) vs the 26-tile version -> all 8 blocks/CU co-resident.
// xt stride 16 (16B-aligned, compile-time) -> 3x ds_read_b128 + b32 per c.
__global__ void __launch_bounds__(128) k_audio_attn(
    const float* __restrict__ x,
    const float* __restrict__ wq1, const float* __restrict__ bq1,
    const float* __restrict__ wk1, const float* __restrict__ bk1,
    const float* __restrict__ wv1, const float* __restrict__ bv1,
    const float* __restrict__ wq2, const float* __restrict__ bq2,
    const float* __restrict__ wk2, const float* __restrict__ bk2,
    const float* __restrict__ wv2, const float* __restrict__ bv2,
    float* __restrict__ afeat, float* __restrict__ xgap) {
    int b = blockIdx.x, n = blockIdx.y, stage = blockIdx.z;
    const float* wq = stage ? wq2 : wq1; const float* bq = stage ? bq2 : bq1;
    const float* wk = stage ? wk2 : wk1; const float* bk = stage ? bk2 : bk1;
    const float* wv = stage ? wv2 : wv1; const float* bv = stage ? bv2 : bv1;
    __shared__ float xt[96 * 16];          // 6144 B
    __shared__ float sb[96 * 15];          // 5760 B
    __shared__ float pmax[8][13], psum[8][13];
    __shared__ float mx[13], sm[13];
    int tid = threadIdx.x;
    bool act = tid < 96;
    int o = act ? tid : 0;
    float bqv = act ? bq[n * 96 + tid] : 0.f;
    float bkv = act ? bk[n * 96 + tid] : 0.f;
    float bvv = act ? bv[n * 96 + tid] : 0.f;
    const float* wqb = wq + n * 9216 + o;   // [c][o] layout -> wqb[c*96]
    const float* wkb = wk + n * 9216 + o;
    const float* wvb = wv + n * 9216 + o;
    const bool do_gap = (n == 0 && stage == 0);
    float accO = 0.f, xsum = 0.f;
    const float* xb = x + (size_t)b * 96 * 234;
    for (int tile = 0; tile < 18; ++tile) {
        int p0 = tile * 13;
        __syncthreads();
        for (int e = tid; e < 1248; e += 128) {
            int c = e / 13, pp = e - c * 13;
            xt[c * 16 + pp] = xb[c * 234 + p0 + pp];
        }
        __syncthreads();
        if (do_gap && act) {
            const float* xr = xt + o * 16;
            #pragma unroll
            for (int p = 0; p < 13; ++p) xsum += xr[p];
        }
        float aq[13], ak[13], av[13];
        #pragma unroll
        for (int p = 0; p < 13; ++p) { aq[p] = bqv; ak[p] = bkv; av[p] = bvv; }
        for (int c = 0; c < 96; ++c) {
            float wqv = wqb[c * 96], wkv = wkb[c * 96], wvv2 = wvb[c * 96];
            const float* xr = xt + c * 16;
            #pragma unroll
            for (int q4 = 0; q4 < 3; ++q4) {
                float4 x4 = *(const float4*)(xr + q4 * 4);
                int p = q4 * 4;
                aq[p]   += wqv * x4.x; ak[p]   += wkv * x4.x; av[p]   += wvv2 * x4.x;
                aq[p+1] += wqv * x4.y; ak[p+1] += wkv * x4.y; av[p+1] += wvv2 * x4.y;
                aq[p+2] += wqv * x4.z; ak[p+2] += wkv * x4.z; av[p+2] += wvv2 * x4.z;
                aq[p+3] += wqv * x4.w; ak[p+3] += wkv * x4.w; av[p+3] += wvv2 * x4.w;
            }
            float xl = xr[12];
            aq[12] += wqv * xl; ak[12] += wkv * xl; av[12] += wvv2 * xl;
        }
        if (act) {
            #pragma unroll
            for (int p = 0; p < 13; ++p)
                sb[o * 15 + p] = aq[p] * ak[p];
        }
        __syncthreads();
        // two-stage max over o (96 = 8 chunks of 12), 104 threads
        if (tid < 104) {
            int p = tid % 13, ch = tid / 13;
            int o0 = ch * 12;
            float m_ = -1e30f;
            for (int q = 0; q < 12; ++q) m_ = fmaxf(m_, sb[(o0 + q) * 15 + p]);
            pmax[ch][p] = m_;
        }
        __syncthreads();
        if (tid < 13) {
            float m_ = pmax[0][tid];
            #pragma unroll
            for (int ch = 1; ch < 8; ++ch) m_ = fmaxf(m_, pmax[ch][tid]);
            mx[tid] = m_;
        }
        __syncthreads();
        // two-stage sum of exp
        if (tid < 104) {
            int p = tid % 13, ch = tid / 13;
            int o0 = ch * 12;
            float mv = mx[p];
            float s_ = 0.f;
            for (int q = 0; q < 12; ++q) s_ += __expf(sb[(o0 + q) * 15 + p] - mv);
            psum[ch][p] = s_;
        }
        __syncthreads();
        if (tid < 13) {
            float s_ = psum[0][tid];
            #pragma unroll
            for (int ch = 1; ch < 8; ++ch) s_ += psum[ch][tid];
            sm[tid] = s_;
        }
        __syncthreads();
        if (act) {
            #pragma unroll
            for (int p = 0; p < 13; ++p)
                accO += __expf(sb[o * 15 + p] - mx[p]) / sm[p] * av[p];
        }
    }
    if (act) afeat[b * 1536 + n * 192 + stage * 96 + tid] = accO * (1.f / 234.f);
    if (do_gap && act) xgap[b * 96 + tid] = xsum * (1.f / 234.f);
}

// ---------- embedding lookup + input-side GRU GEMM, 8 rows/block ----------
__global__ void __launch_bounds__(320) k_gi(const int* __restrict__ tokens,
        const float* __restrict__ emb, const float* __restrict__ w_ih,
        const float* __restrict__ b_ih, float* __restrict__ GI) {
    int r0 = blockIdx.x * 8;
    int tid = threadIdx.x;
    __shared__ float er[8][200];
    for (int e = tid; e < 1600; e += 320) {
        int r = e / 200, c = e - r * 200;
        er[r][c] = emb[(size_t)tokens[r0 + r] * 200 + c];
    }
    __syncthreads();
    if (tid < 300) {
        float acc[8];
        float bv = b_ih[tid];
        #pragma unroll
        for (int r = 0; r < 8; ++r) acc[r] = bv;
        for (int k4 = 0; k4 < 50; ++k4) {
            float4 w4 = *(const float4*)(w_ih + (size_t)tid * 200 + k4 * 4);
            #pragma unroll
            for (int r = 0; r < 8; ++r) {
                float4 x4 = *(const float4*)&er[r][k4 * 4];
                acc[r] += w4.x * x4.x + w4.y * x4.y + w4.z * x4.z + w4.w * x4.w;
            }
        }
        #pragma unroll
        for (int r = 0; r < 8; ++r)
            GI[(size_t)(r0 + r) * 300 + tid] = acc[r];
    }
}

// ---------- whole GRU recurrence in ONE kernel (one block per batch row) ----------
__global__ void __launch_bounds__(320) k_gru_all(const float* __restrict__ GI,
        const float* __restrict__ w_hh, const float* __restrict__ b_hh,
        float* __restrict__ outs) {
    int b = blockIdx.x, tid = threadIdx.x;
    __shared__ float hs[100];
    __shared__ float gH[300];
    float4 wreg[25];
    float bias = 0.f;
    if (tid < 300) {
        bias = b_hh[tid];
        #pragma unroll
        for (int k4 = 0; k4 < 25; ++k4)
            wreg[k4] = *(const float4*)(w_hh + (size_t)tid * 100 + k4 * 4);
    }
    if (tid < 100) hs[tid] = 0.f;
    __syncthreads();
    for (int t = 0; t < kT; ++t) {
        if (tid < 300) {
            float gh = bias;
            #pragma unroll
            for (int k4 = 0; k4 < 25; ++k4) {
                float4 h4 = *(const float4*)&hs[k4 * 4];
                gh += wreg[k4].x * h4.x + wreg[k4].y * h4.y
                    + wreg[k4].z * h4.z + wreg[k4].w * h4.w;
            }
            gH[tid] = gh;
        }
        __syncthreads();
        if (tid < 100) {
            const float* gi = GI + ((size_t)b * kT + t) * 300;
            float r = 1.f / (1.f + expf(-(gi[tid] + gH[tid])));
            float z = 1.f / (1.f + expf(-(gi[100 + tid] + gH[100 + tid])));
            float nn = tanhf(gi[200 + tid] + r * gH[200 + tid]);
            float h2 = (1.f - z) * nn + z * hs[tid];
            hs[tid] = h2;
            outs[((size_t)b * kT + t) * 100 + tid] = h2;
        }
        __syncthreads();
    }
}

// ---------- fused text attention (both stages), t-tiled, shuffle softmax ----------
__global__ void __launch_bounds__(128) k_text_attn(const float* __restrict__ outs,
    const float* __restrict__ wq1, const float* __restrict__ bq1,
    const float* __restrict__ wk1, const float* __restrict__ bk1,
    const float* __restrict__ wv1, const float* __restrict__ bv1,
    const float* __restrict__ wq2, const float* __restrict__ bq2,
    const float* __restrict__ wk2, const float* __restrict__ bk2,
    const float* __restrict__ wv2, const float* __restrict__ bv2,
    float* __restrict__ tfeat) {
    int b = blockIdx.x, stage = blockIdx.y, n = blockIdx.z;
    const float* wq = stage ? wq2 : wq1; const float* bq = stage ? bq2 : bq1;
    const float* wk = stage ? wk2 : wk1; const float* bk = stage ? bk2 : bk1;
    const float* wv = stage ? wv2 : wv1; const float* bv = stage ? bv2 : bv1;
    int tid = threadIdx.x;
    bool act = tid < 96;
    int oo = act ? tid : 0;
    const float* wqr = wq + ((size_t)n * 96 + oo) * 100;
    const float* wkr = wk + ((size_t)n * 96 + oo) * 100;
    const float* wvr = wv + ((size_t)n * 96 + oo) * 100;
    float bqv = act ? bq[n * 96 + tid] : 0.f;
    float bkv = act ? bk[n * 96 + tid] : 0.f;
    float bvv = act ? bv[n * 96 + tid] : 0.f;
    __shared__ float rows[10][100];
    __shared__ float wredM[2][10], wredS[2][10];
    float acc = 0.f;
    int wave = tid >> 6, lane = tid & 63;
    for (int tile = 0; tile < 5; ++tile) {
        int t0 = tile * 10;
        __syncthreads();
        for (int e = tid; e < 1000; e += 128) {
            int tt = e / 100, c = e - tt * 100;
            rows[tt][c] = outs[((size_t)b * kT + t0 + tt) * 100 + c];
        }
        __syncthreads();
        float q[10], k[10], v[10];
        #pragma unroll
        for (int tt = 0; tt < 10; ++tt) { q[tt] = bqv; k[tt] = bkv; v[tt] = bvv; }
        for (int c4 = 0; c4 < 25; ++c4) {
            float4 aq = *(const float4*)(wqr + c4 * 4);
            float4 ak = *(const float4*)(wkr + c4 * 4);
            float4 av = *(const float4*)(wvr + c4 * 4);
            #pragma unroll
            for (int tt = 0; tt < 10; ++tt) {
                float4 x4 = *(const float4*)&rows[tt][c4 * 4];
                q[tt] += aq.x * x4.x + aq.y * x4.y + aq.z * x4.z + aq.w * x4.w;
                k[tt] += ak.x * x4.x + ak.y * x4.y + ak.z * x4.z + ak.w * x4.w;
                v[tt] += av.x * x4.x + av.y * x4.y + av.z * x4.z + av.w * x4.w;
            }
        }
        float s[10], e_[10];
        #pragma unroll
        for (int tt = 0; tt < 10; ++tt) s[tt] = act ? q[tt] * k[tt] : -1e30f;
        #pragma unroll
        for (int tt = 0; tt < 10; ++tt) {
            float m = s[tt];
            #pragma unroll
            for (int off = 1; off < 64; off <<= 1) m = fmaxf(m, __shfl_xor(m, off));
            if (lane == 0) wredM[wave][tt] = m;
        }
        __syncthreads();
        #pragma unroll
        for (int tt = 0; tt < 10; ++tt) {
            float mx = fmaxf(wredM[0][tt], wredM[1][tt]);
            e_[tt] = expf(s[tt] - mx);
        }
        #pragma unroll
        for (int tt = 0; tt < 10; ++tt) {
            float sm = e_[tt];
            #pragma unroll
            for (int off = 1; off < 64; off <<= 1) sm += __shfl_xor(sm, off);
            if (lane == 0) wredS[wave][tt] = sm;
        }
        __syncthreads();
        #pragma unroll
        for (int tt = 0; tt < 10; ++tt) {
            float sm = wredS[0][tt] + wredS[1][tt];
            acc += e_[tt] / sm * v[tt];
        }
    }
    if (act) tfeat[b * 1536 + stage * 768 + n * 96 + tid] = acc;
}

// ---------- cross-modal gated fusion + final logits ----------
__global__ void __launch_bounds__(128) k_final(const float* __restrict__ xgap,
    const float* __restrict__ outs, const float* __restrict__ afeat,
    const float* __restrict__ tfeat,
    const float* __restrict__ w_fa, const float* __restrict__ b_fa,
    const float* __restrict__ w_ft, const float* __restrict__ b_ft,
    const float* __restrict__ w_e, const float* __restrict__ b_e,
    float* __restrict__ out) {
    int b = blockIdx.x; int tid = threadIdx.x;
    __shared__ float xg[96], hv[100], st[100], sa[96], aat[96], atba[100];
    __shared__ float redm[2], reds[2];
    if (tid < 96) xg[tid] = xgap[b * 96 + tid];
    if (tid < 100) hv[tid] = outs[(size_t)(b * kT + kT - 1) * 100 + tid];
    __syncthreads();
    if (tid < 100) {
        float acc = b_fa[tid];
        const float* wr = w_fa + tid * 96;
        for (int c = 0; c < 96; ++c) acc += wr[c] * xg[c];
        st[tid] = acc;
    }
    if (tid < 96) {
        float acc = b_ft[tid];
        const float* wr = w_ft + tid * 100;
        for (int c = 0; c < 100; ++c) acc += wr[c] * hv[c];
        sa[tid] = acc;
    }
    __syncthreads();
    if (tid == 0) {
        float mxv = -1e30f; for (int i = 0; i < 100; ++i) mxv = fmaxf(mxv, st[i]);
        float s = 0.f; for (int i = 0; i < 100; ++i) s += expf(st[i] - mxv);
        redm[0] = mxv; reds[0] = s;
    }
    if (tid == 1) {
        float mxv = -1e30f; for (int i = 0; i < 96; ++i) mxv = fmaxf(mxv, sa[i]);
        float s = 0.f; for (int i = 0; i < 96; ++i) s += expf(sa[i] - mxv);
        redm[1] = mxv; reds[1] = s;
    }
    __syncthreads();
    if (tid < 100) atba[tid] = expf(st[tid] - redm[0]) / reds[0] * hv[tid];
    if (tid < 96)  aat[tid]  = expf(sa[tid] - redm[1]) / reds[1] * xg[tid];
    __syncthreads();
    float a0 = 0.f, a1 = 0.f, a2 = 0.f, a3 = 0.f;
    for (int col = tid; col < 3268; col += 128) {
        float f;
        if (col < 1536)      f = afeat[b * 1536 + col];
        else if (col < 3072) f = tfeat[b * 1536 + col - 1536];
        else if (col < 3168) f = aat[col - 3072];
        else                 f = atba[col - 3168];
        a0 += w_e[col] * f;            a1 += w_e[3268 + col] * f;
        a2 += w_e[2 * 3268 + col] * f; a3 += w_e[3 * 3268 + col] * f;
    }
    __shared__ float r4[4][128];
    r4[0][tid] = a0; r4[1][tid] = a1; r4[2][tid] = a2; r4[3][tid] = a3;
    __syncthreads();
    if (tid < 4) {
        float s = 0.f;
        for (int i = 0; i < 128; ++i) s += r4[tid][i];
        out[b * 4 + tid] = s + b_e[tid];
    }
}

// =====================================================================
extern "C" void kernel_launch(void* const* d_in, const int* in_sizes, int n_in,
                              void* d_out, int out_size, void* d_ws, size_t ws_size,
                              hipStream_t stream) {
    (void)in_sizes; (void)n_in; (void)out_size; (void)ws_size;
    const float* mfcc_t = (const float*)d_in[0];
    const float* mfcc_f = (const float*)d_in[1];
    const float* mfcc_c = (const float*)d_in[2];
    const int*   tokens = (const int*)d_in[3];
    const float *w1a = (const float*)d_in[5],  *b1a = (const float*)d_in[6],
                *g1a = (const float*)d_in[7],  *be1a = (const float*)d_in[8],
                *m1a = (const float*)d_in[9],  *v1a = (const float*)d_in[10];
    const float *w1b = (const float*)d_in[11], *b1b = (const float*)d_in[12],
                *g1b = (const float*)d_in[13], *be1b = (const float*)d_in[14],
                *m1b = (const float*)d_in[15], *v1b = (const float*)d_in[16];
    const float *w2 = (const float*)d_in[17], *b2 = (const float*)d_in[18],
                *g2 = (const float*)d_in[19], *be2 = (const float*)d_in[20],
                *m2 = (const float*)d_in[21], *v2 = (const float*)d_in[22];
    const float *w3 = (const float*)d_in[23], *b3 = (const float*)d_in[24],
                *g3 = (const float*)d_in[25], *be3 = (const float*)d_in[26],
                *m3 = (const float*)d_in[27], *v3 = (const float*)d_in[28];
    const float *w4 = (const float*)d_in[29], *b4 = (const float*)d_in[30],
                *g4 = (const float*)d_in[31], *be4 = (const float*)d_in[32],
                *m4 = (const float*)d_in[33], *v4 = (const float*)d_in[34];
    const float *wq_a1 = (const float*)d_in[35], *bq_a1 = (const float*)d_in[36],
                *wk_a1 = (const float*)d_in[37], *bk_a1 = (const float*)d_in[38],
                *wv_a1 = (const float*)d_in[39], *bv_a1 = (const float*)d_in[40];
    const float *wq_a2 = (const float*)d_in[41], *bq_a2 = (const float*)d_in[42],
                *wk_a2 = (const float*)d_in[43], *bk_a2 = (const float*)d_in[44],
                *wv_a2 = (const float*)d_in[45], *bv_a2 = (const float*)d_in[46];
    const float *emb  = (const float*)d_in[47];
    const float *w_ih = (const float*)d_in[48], *w_hh = (const float*)d_in[49],
                *b_ih = (const float*)d_in[50], *b_hh = (const float*)d_in[51];
    const float *wq_t1 = (const float*)d_in[52], *bq_t1 = (const float*)d_in[53],
                *wk_t1 = (const float*)d_in[54], *bk_t1 = (const float*)d_in[55],
                *wv_t1 = (const float*)d_in[56], *bv_t1 = (const float*)d_in[57];
    const float *wq_t2 = (const float*)d_in[58], *bq_t2 = (const float*)d_in[59],
                *wk_t2 = (const float*)d_in[60], *bk_t2 = (const float*)d_in[61],
                *wv_t2 = (const float*)d_in[62], *bv_t2 = (const float*)d_in[63];
    const float *w_fa = (const float*)d_in[64], *b_fa = (const float*)d_in[65],
                *w_ft = (const float*)d_in[66], *b_ft = (const float*)d_in[67],
                *w_e  = (const float*)d_in[68], *b_e  = (const float*)d_in[69];

    float* ws = (float*)d_ws;
    const size_t Z0 = 0;                 // c2 -> c3 -> x4
    const size_t Z1 = 22091776ull;       // x1 -> p2 -> p3 -> GI
    const size_t OUTS  = 34072576ull;    // conv-wT (early) then GRU outputs
    const size_t AFEAT = 34712576ull;
    const size_t TFEAT = 34909184ull;
    const size_t XGAP  = 35105792ull;
    const size_t WT    = 35118080ull;
    float* X1 = ws + Z1;
    float* C2 = ws + Z0;  float* P2 = ws + Z1;
    float* C3 = ws + Z0;  float* P3 = ws + Z1;
    float* X4 = ws + Z0;  float* GI = ws + Z1;
    float* outs  = ws + OUTS;
    float* afeat = ws + AFEAT;
    float* tfeat = ws + TFEAT;
    float* xgap  = ws + XGAP;
    float* wqa1t = ws + WT;
    float* wka1t = wqa1t + 73728; float* wva1t = wka1t + 73728;
    float* wqa2t = wva1t + 73728; float* wka2t = wqa2t + 73728; float* wva2t = wka2t + 73728;
    // conv weight transposes parked in the (still dead) GRU outs region
    float* wT2 = outs;            //  6,912
    float* wT3 = outs + 6912;     // 18,432
    float* wT4 = outs + 25344;    // 55,296

    // ----- all weight transposes in ONE launch -----
    TPack tp;
    tp.d[0] = {wq_a1, wqa1t, 96, 96, 73728};
    tp.d[1] = {wk_a1, wka1t, 96, 96, 73728};
    tp.d[2] = {wv_a1, wva1t, 96, 96, 73728};
    tp.d[3] = {wq_a2, wqa2t, 96, 96, 73728};
    tp.d[4] = {wk_a2, wka2t, 96, 96, 73728};
    tp.d[5] = {wv_a2, wva2t, 96, 96, 73728};
    tp.d[6] = {w2, wT2, 32, 216, 6912};
    tp.d[7] = {w3, wT3, 64, 288, 18432};
    tp.d[8] = {w4, wT4, 96, 576, 55296};
    k_transpose_pack<<<dim3(288, 9), 256, 0, stream>>>(tp);

    // ----- fused stem (conv1 x3 + BN + ReLU + resize + concat) -----
    k_stem<<<46800, 256, 0, stream>>>(mfcc_t, mfcc_f, mfcc_c,
        w1a, b1a, g1a, be1a, m1a, v1a,
        w1b, b1b, g1b, be1b, m1b, v1b, X1, 11980800);
    k_conv3x3_tiled<24, 8, 25, 156, 9, 6><<<dim3(128, 3, 4), 256, 0, stream>>>(
        X1, wT2, b2, g2, be2, m2, v2, C2, 32);
    k_maxpool<<<14976, 256, 0, stream>>>(C2, P2, 32, 25, 156, 12, 78, 3833856);
    k_conv3x3_tiled<32, 8, 12, 78, 12, 4><<<dim3(128, 1, 8), 256, 0, stream>>>(
        P2, wT3, b3, g3, be3, m3, v3, C3, 64);
    k_maxpool<<<7488, 256, 0, stream>>>(C3, P3, 64, 12, 78, 6, 39, 1916928);
    k_conv3x3_tiled<64, 16, 6, 39, 6, 1><<<dim3(128, 1, 12), 256, 0, stream>>>(
        P3, wT4, b4, g4, be4, m4, v4, X4, 96);

    // ----- audio attention (+GAP folded in) -----
    k_audio_attn<<<dim3(kB, 8, 2), 128, 0, stream>>>(X4,
        wqa1t, bq_a1, wka1t, bk_a1, wva1t, bv_a1,
        wqa2t, bq_a2, wka2t, bk_a2, wva2t, bv_a2, afeat, xgap);

    // ----- text branch -----
    k_gi<<<kB * kT / 8, 320, 0, stream>>>(tokens, emb, w_ih, b_ih, GI);
    k_gru_all<<<kB, 320, 0, stream>>>(GI, w_hh, b_hh, outs);
    k_text_attn<<<dim3(kB, 2, 8), 128, 0, stream>>>(outs,
        wq_t1, bq_t1, wk_t1, bk_t1, wv_t1, bv_t1,
        wq_t2, bq_t2, wk_t2, bk_t2, wv_t2, bv_t2, tfeat);

    // ----- fusion + logits -----
    k_final<<<kB, 128, 0, stream>>>(xgap, outs, afeat, tfeat,
                                    w_fa, b_fa, w_ft, b_ft, w_e, b_e, (float*)d_out);
}

// Round 8
// 1780.866 us; speedup vs baseline: 1.0499x; 1.0499x over previous
//
#include <hip/hip_runtime.h>
#include <math.h>

// ---------------- constants ----------------
static constexpr int kB = 128;
static constexpr int kT = 50;

// ---------- packed transpose [N][O][C] -> [N][C][O], 9 segments, one launch ----------
struct TDesc { const float* src; float* dst; int O; int C; int total; };
struct TPack { TDesc d[9]; };
__global__ void k_transpose_pack(TPack p) {
    TDesc t = p.d[blockIdx.y];
    int idx = blockIdx.x * 256 + threadIdx.x;
    if (idx >= t.total) return;
    int o = idx % t.O; int r = idx / t.O; int c = r % t.C; int n = r / t.C;
    t.dst[idx] = t.src[((size_t)n * t.O + o) * t.C + c];
}

// ---------- conv (Cin=1, Cout=8, VALID) + BN(eval) + ReLU ----------
__global__ void k_conv1_bn_relu(const float* __restrict__ in, const float* __restrict__ w,
                                const float* __restrict__ cb, const float* __restrict__ g,
                                const float* __restrict__ be, const float* __restrict__ m,
                                const float* __restrict__ v, float* __restrict__ out,
                                int Hin, int Win, int Hout, int Wout, int KH, int KW, int total) {
    int idx = blockIdx.x * blockDim.x + threadIdx.x;
    if (idx >= total) return;
    int ox = idx % Wout; int t = idx / Wout;
    int oy = t % Hout; t /= Hout;
    int oc = t % 8; int b = t / 8;
    const float* ip = in + (b * Hin + oy) * Win + ox;
    const float* wp = w + oc * KH * KW;
    float acc = 0.f;
    for (int ky = 0; ky < KH; ++ky)
        for (int kx = 0; kx < KW; ++kx)
            acc += ip[ky * Win + kx] * wp[ky * KW + kx];
    float s = g[oc] * rsqrtf(v[oc] + 1e-5f);
    float bias = (cb[oc] - m[oc]) * s + be[oc];
    out[idx] = fmaxf(acc * s + bias, 0.f);
}

// ---------- half-pixel bilinear resize (no antialias) + channel concat ----------
__global__ void k_resize_concat(const float* __restrict__ xa, const float* __restrict__ xb,
                                const float* __restrict__ xc, float* __restrict__ out, int total) {
    int idx = blockIdx.x * blockDim.x + threadIdx.x;
    if (idx >= total) return;
    int ox = idx % 156; int t = idx / 156;
    int oy = t % 25; t /= 25;
    int ch = t % 24; int b = t / 24;
    int grp = ch >> 3, c = ch & 7;
    const float* src; int Hin, Win;
    if (grp == 0) { src = xa; Hin = 196; Win = 39; }
    else          { src = (grp == 1 ? xb : xc); Hin = 199; Win = 35; }
    float sy = (oy + 0.5f) * ((float)Hin / 25.f) - 0.5f;
    float sx = (ox + 0.5f) * ((float)Win / 156.f) - 0.5f;
    float fy0 = floorf(sy), fx0 = floorf(sx);
    float fy = sy - fy0, fx = sx - fx0;
    int y0 = (int)fy0, x0 = (int)fx0;
    int y0c = min(max(y0, 0), Hin - 1), y1c = min(max(y0 + 1, 0), Hin - 1);
    int x0c = min(max(x0, 0), Win - 1), x1c = min(max(x0 + 1, 0), Win - 1);
    const float* p = src + (size_t)(b * 8 + c) * Hin * Win;
    float v00 = p[y0c * Win + x0c], v01 = p[y0c * Win + x1c];
    float v10 = p[y1c * Win + x0c], v11 = p[y1c * Win + x1c];
    out[idx] = v00 * (1.f - fy) * (1.f - fx) + v01 * (1.f - fy) * fx
             + v10 * fy * (1.f - fx) + v11 * fy * fx;
}

// ---------- LDS-tiled 3x3 conv, pad 1, fused BN(eval) + ReLU ----------
template<int CIN, int CI_T, int H, int W, int ROWS, int NPX>
__global__ void __launch_bounds__(256) k_conv3x3_tiled(
    const float* __restrict__ in, const float* __restrict__ wT,
    const float* __restrict__ cb, const float* __restrict__ g,
    const float* __restrict__ be, const float* __restrict__ m,
    const float* __restrict__ v, float* __restrict__ out, int COUT) {
    constexpr int WP = W + 2;
    constexpr int RP = ROWS + 2;
    constexpr int STAGE = CI_T * RP * WP;
    __shared__ float sx[STAGE];
    __shared__ float sw[CI_T * 9 * 8];
    const int b = blockIdx.x, rt = blockIdx.y, oc0 = blockIdx.z * 8;
    const int row0 = rt * ROWS;
    const int tid = threadIdx.x;

    int off[NPX]; bool val[NPX];
    #pragma unroll
    for (int j = 0; j < NPX; ++j) {
        int px = tid + j * 256;
        int oy = px / W, ox = px - oy * W;
        bool ok = (px < ROWS * W) && (row0 + oy < H);
        val[j] = ok;
        off[j] = ok ? (oy * WP + ox) : 0;
    }

    float acc[NPX][8];
    #pragma unroll
    for (int j = 0; j < NPX; ++j)
        #pragma unroll
        for (int o = 0; o < 8; ++o) acc[j][o] = 0.f;

    for (int c0 = 0; c0 < CIN; c0 += CI_T) {
        __syncthreads();
        for (int e = tid; e < STAGE; e += 256) {
            int ci = e / (RP * WP);
            int rem = e - ci * RP * WP;
            int r = rem / WP;
            int xx = rem - r * WP;
            int iy = row0 - 1 + r;
            int ix = xx - 1;
            float vv = 0.f;
            if (iy >= 0 && iy < H && ix >= 0 && ix < W)
                vv = in[((size_t)(b * CIN + c0 + ci) * H + iy) * W + ix];
            sx[e] = vv;
        }
        for (int e = tid; e < CI_T * 9 * 8; e += 256) {
            int rk = e >> 3;
            int o = e & 7;
            sw[e] = wT[((size_t)c0 * 9 + rk) * COUT + oc0 + o];
        }
        __syncthreads();
        #pragma unroll 1
        for (int cl = 0; cl < CI_T; ++cl) {
            const float* sxc = sx + cl * RP * WP;
            #pragma unroll
            for (int k = 0; k < 9; ++k) {
                const int ky = k / 3, kx = k % 3;
                const float4 wa = *(const float4*)(sw + (cl * 9 + k) * 8);
                const float4 wb = *(const float4*)(sw + (cl * 9 + k) * 8 + 4);
                #pragma unroll
                for (int j = 0; j < NPX; ++j) {
                    float xv = sxc[off[j] + ky * WP + kx];
                    acc[j][0] += xv * wa.x; acc[j][1] += xv * wa.y;
                    acc[j][2] += xv * wa.z; acc[j][3] += xv * wa.w;
                    acc[j][4] += xv * wb.x; acc[j][5] += xv * wb.y;
                    acc[j][6] += xv * wb.z; acc[j][7] += xv * wb.w;
                }
            }
        }
    }
    float sc[8], bi[8];
    #pragma unroll
    for (int o = 0; o < 8; ++o) {
        float s = g[oc0 + o] * rsqrtf(v[oc0 + o] + 1e-5f);
        sc[o] = s; bi[o] = (cb[oc0 + o] - m[oc0 + o]) * s + be[oc0 + o];
    }
    #pragma unroll
    for (int j = 0; j < NPX; ++j) if (val[j]) {
        int px = tid + j * 256;
        int oy = row0 + px / W, ox = px % W;
        #pragma unroll
        for (int o = 0; o < 8; ++o)
            out[((size_t)(b * COUT + oc0 + o) * H + oy) * W + ox] =
                fmaxf(acc[j][o] * sc[o] + bi[o], 0.f);
    }
}

// ---------- 2x2 maxpool stride 2 (VALID) ----------
__global__ void k_maxpool(const float* __restrict__ in, float* __restrict__ out,
                          int C, int Hin, int Win, int Hout, int Wout, int total) {
    int idx = blockIdx.x * blockDim.x + threadIdx.x;
    if (idx >= total) return;
    int ox = idx % Wout; int t = idx / Wout;
    int oy = t % Hout; t /= Hout;
    int c = t % C; int b = t / C;
    const float* p = in + ((size_t)(b * C + c) * Hin + 2 * oy) * Win + 2 * ox;
    float m0 = fmaxf(p[0], p[1]);
    float m1 = fmaxf(p[Win], p[Win + 1]);
    out[idx] = fmaxf(m0, m1);
}

// ---------- fused audio attention (both stages) + spatial GAP ----------
// EXACT R5 structure (measured 563 us, best of family): xt stride 28 (b128 reads),
// sb stride 27, bias-init accumulators, two-stage softmax reduce (4 chunks of 24),
// GAP folded into (n==0,stage==0) blocks. TILE_P=26 is the measured optimum:
// 26 FMAs per global weight-load; halving the tile (R6) doubled weight-load issue
// and regressed 563->795 despite better occupancy.
__global__ void __launch_bounds__(128) k_audio_attn(
    const float* __restrict__ x,
    const float* __restrict__ wq1, const float* __restrict__ bq1,
    const float* __restrict__ wk1, const float* __restrict__ bk1,
    const float* __restrict__ wv1, const float* __restrict__ bv1,
    const float* __restrict__ wq2, const float* __restrict__ bq2,
    const float* __restrict__ wk2, const float* __restrict__ bk2,
    const float* __restrict__ wv2, const float* __restrict__ bv2,
    float* __restrict__ afeat, float* __restrict__ xgap) {
    int b = blockIdx.x, n = blockIdx.y, stage = blockIdx.z;
    const float* wq = stage ? wq2 : wq1; const float* bq = stage ? bq2 : bq1;
    const float* wk = stage ? wk2 : wk1; const float* bk = stage ? bk2 : bk1;
    const float* wv = stage ? wv2 : wv1; const float* bv = stage ? bv2 : bv1;
    __shared__ float xt[96 * 28];
    __shared__ float sb[96 * 27];
    __shared__ float pmax[4][26], psum[4][26];
    __shared__ float mx[26], sm[26];
    int tid = threadIdx.x;
    bool act = tid < 96;
    int o = act ? tid : 0;
    float bqv = act ? bq[n * 96 + tid] : 0.f;
    float bkv = act ? bk[n * 96 + tid] : 0.f;
    float bvv = act ? bv[n * 96 + tid] : 0.f;
    const float* wqb = wq + n * 9216 + o;   // [c][o] layout -> wqb[c*96]
    const float* wkb = wk + n * 9216 + o;
    const float* wvb = wv + n * 9216 + o;
    const bool do_gap = (n == 0 && stage == 0);
    float accO = 0.f, xsum = 0.f;
    const float* xb = x + (size_t)b * 96 * 234;
    for (int tile = 0; tile < 9; ++tile) {
        int p0 = tile * 26;
        __syncthreads();
        for (int e = tid; e < 2496; e += 128) {
            int c = e / 26, pp = e - c * 26;
            xt[c * 28 + pp] = xb[c * 234 + p0 + pp];
        }
        __syncthreads();
        if (do_gap && act) {
            const float* xr = xt + o * 28;
            #pragma unroll
            for (int p = 0; p < 26; ++p) xsum += xr[p];
        }
        float aq[26], ak[26], av[26];
        #pragma unroll
        for (int p = 0; p < 26; ++p) { aq[p] = bqv; ak[p] = bkv; av[p] = bvv; }
        for (int c = 0; c < 96; ++c) {
            float wqv = wqb[c * 96], wkv = wkb[c * 96], wvv2 = wvb[c * 96];
            const float* xr = xt + c * 28;
            #pragma unroll
            for (int q4 = 0; q4 < 6; ++q4) {
                float4 x4 = *(const float4*)(xr + q4 * 4);
                int p = q4 * 4;
                aq[p]   += wqv * x4.x; ak[p]   += wkv * x4.x; av[p]   += wvv2 * x4.x;
                aq[p+1] += wqv * x4.y; ak[p+1] += wkv * x4.y; av[p+1] += wvv2 * x4.y;
                aq[p+2] += wqv * x4.z; ak[p+2] += wkv * x4.z; av[p+2] += wvv2 * x4.z;
                aq[p+3] += wqv * x4.w; ak[p+3] += wkv * x4.w; av[p+3] += wvv2 * x4.w;
            }
            float2 x2 = *(const float2*)(xr + 24);
            aq[24] += wqv * x2.x; ak[24] += wkv * x2.x; av[24] += wvv2 * x2.x;
            aq[25] += wqv * x2.y; ak[25] += wkv * x2.y; av[25] += wvv2 * x2.y;
        }
        if (act) {
            #pragma unroll
            for (int p = 0; p < 26; ++p)
                sb[o * 27 + p] = aq[p] * ak[p];
        }
        __syncthreads();
        // two-stage max over o (96 = 4 chunks of 24)
        if (tid < 104) {
            int p = tid % 26, ch = tid / 26;
            int o0 = ch * 24;
            float m_ = -1e30f;
            for (int q = 0; q < 24; ++q) m_ = fmaxf(m_, sb[(o0 + q) * 27 + p]);
            pmax[ch][p] = m_;
        }
        __syncthreads();
        if (tid < 26)
            mx[tid] = fmaxf(fmaxf(pmax[0][tid], pmax[1][tid]),
                            fmaxf(pmax[2][tid], pmax[3][tid]));
        __syncthreads();
        // two-stage sum of exp
        if (tid < 104) {
            int p = tid % 26, ch = tid / 26;
            int o0 = ch * 24;
            float mv = mx[p];
            float s_ = 0.f;
            for (int q = 0; q < 24; ++q) s_ += __expf(sb[(o0 + q) * 27 + p] - mv);
            psum[ch][p] = s_;
        }
        __syncthreads();
        if (tid < 26)
            sm[tid] = psum[0][tid] + psum[1][tid] + psum[2][tid] + psum[3][tid];
        __syncthreads();
        if (act) {
            #pragma unroll
            for (int p = 0; p < 26; ++p)
                accO += __expf(sb[o * 27 + p] - mx[p]) / sm[p] * av[p];
        }
    }
    if (act) afeat[b * 1536 + n * 192 + stage * 96 + tid] = accO * (1.f / 234.f);
    if (do_gap && act) xgap[b * 96 + tid] = xsum * (1.f / 234.f);
}

// ---------- embedding lookup + input-side GRU GEMM, 8 rows/block ----------
__global__ void __launch_bounds__(320) k_gi(const int* __restrict__ tokens,
        const float* __restrict__ emb, const float* __restrict__ w_ih,
        const float* __restrict__ b_ih, float* __restrict__ GI) {
    int r0 = blockIdx.x * 8;
    int tid = threadIdx.x;
    __shared__ float er[8][200];
    for (int e = tid; e < 1600; e += 320) {
        int r = e / 200, c = e - r * 200;
        er[r][c] = emb[(size_t)tokens[r0 + r] * 200 + c];
    }
    __syncthreads();
    if (tid < 300) {
        float acc[8];
        float bv = b_ih[tid];
        #pragma unroll
        for (int r = 0; r < 8; ++r) acc[r] = bv;
        for (int k4 = 0; k4 < 50; ++k4) {
            float4 w4 = *(const float4*)(w_ih + (size_t)tid * 200 + k4 * 4);
            #pragma unroll
            for (int r = 0; r < 8; ++r) {
                float4 x4 = *(const float4*)&er[r][k4 * 4];
                acc[r] += w4.x * x4.x + w4.y * x4.y + w4.z * x4.z + w4.w * x4.w;
            }
        }
        #pragma unroll
        for (int r = 0; r < 8; ++r)
            GI[(size_t)(r0 + r) * 300 + tid] = acc[r];
    }
}

// ---------- whole GRU recurrence in ONE kernel (one block per batch row) ----------
__global__ void __launch_bounds__(320) k_gru_all(const float* __restrict__ GI,
        const float* __restrict__ w_hh, const float* __restrict__ b_hh,
        float* __restrict__ outs) {
    int b = blockIdx.x, tid = threadIdx.x;
    __shared__ float hs[100];
    __shared__ float gH[300];
    float4 wreg[25];
    float bias = 0.f;
    if (tid < 300) {
        bias = b_hh[tid];
        #pragma unroll
        for (int k4 = 0; k4 < 25; ++k4)
            wreg[k4] = *(const float4*)(w_hh + (size_t)tid * 100 + k4 * 4);
    }
    if (tid < 100) hs[tid] = 0.f;
    __syncthreads();
    for (int t = 0; t < kT; ++t) {
        if (tid < 300) {
            float gh = bias;
            #pragma unroll
            for (int k4 = 0; k4 < 25; ++k4) {
                float4 h4 = *(const float4*)&hs[k4 * 4];
                gh += wreg[k4].x * h4.x + wreg[k4].y * h4.y
                    + wreg[k4].z * h4.z + wreg[k4].w * h4.w;
            }
            gH[tid] = gh;
        }
        __syncthreads();
        if (tid < 100) {
            const float* gi = GI + ((size_t)b * kT + t) * 300;
            float r = 1.f / (1.f + expf(-(gi[tid] + gH[tid])));
            float z = 1.f / (1.f + expf(-(gi[100 + tid] + gH[100 + tid])));
            float nn = tanhf(gi[200 + tid] + r * gH[200 + tid]);
            float h2 = (1.f - z) * nn + z * hs[tid];
            hs[tid] = h2;
            outs[((size_t)b * kT + t) * 100 + tid] = h2;
        }
        __syncthreads();
    }
}

// ---------- fused text attention (both stages), t-tiled, shuffle softmax ----------
__global__ void __launch_bounds__(128) k_text_attn(const float* __restrict__ outs,
    const float* __restrict__ wq1, const float* __restrict__ bq1,
    const float* __restrict__ wk1, const float* __restrict__ bk1,
    const float* __restrict__ wv1, const float* __restrict__ bv1,
    const float* __restrict__ wq2, const float* __restrict__ bq2,
    const float* __restrict__ wk2, const float* __restrict__ bk2,
    const float* __restrict__ wv2, const float* __restrict__ bv2,
    float* __restrict__ tfeat) {
    int b = blockIdx.x, stage = blockIdx.y, n = blockIdx.z;
    const float* wq = stage ? wq2 : wq1; const float* bq = stage ? bq2 : bq1;
    const float* wk = stage ? wk2 : wk1; const float* bk = stage ? bk2 : bk1;
    const float* wv = stage ? wv2 : wv1; const float* bv = stage ? bv2 : bv1;
    int tid = threadIdx.x;
    bool act = tid < 96;
    int oo = act ? tid : 0;
    const float* wqr = wq + ((size_t)n * 96 + oo) * 100;
    const float* wkr = wk + ((size_t)n * 96 + oo) * 100;
    const float* wvr = wv + ((size_t)n * 96 + oo) * 100;
    float bqv = act ? bq[n * 96 + tid] : 0.f;
    float bkv = act ? bk[n * 96 + tid] : 0.f;
    float bvv = act ? bv[n * 96 + tid] : 0.f;
    __shared__ float rows[10][100];
    __shared__ float wredM[2][10], wredS[2][10];
    float acc = 0.f;
    int wave = tid >> 6, lane = tid & 63;
    for (int tile = 0; tile < 5; ++tile) {
        int t0 = tile * 10;
        __syncthreads();
        for (int e = tid; e < 1000; e += 128) {
            int tt = e / 100, c = e - tt * 100;
            rows[tt][c] = outs[((size_t)b * kT + t0 + tt) * 100 + c];
        }
        __syncthreads();
        float q[10], k[10], v[10];
        #pragma unroll
        for (int tt = 0; tt < 10; ++tt) { q[tt] = bqv; k[tt] = bkv; v[tt] = bvv; }
        for (int c4 = 0; c4 < 25; ++c4) {
            float4 aq = *(const float4*)(wqr + c4 * 4);
            float4 ak = *(const float4*)(wkr + c4 * 4);
            float4 av = *(const float4*)(wvr + c4 * 4);
            #pragma unroll
            for (int tt = 0; tt < 10; ++tt) {
                float4 x4 = *(const float4*)&rows[tt][c4 * 4];
                q[tt] += aq.x * x4.x + aq.y * x4.y + aq.z * x4.z + aq.w * x4.w;
                k[tt] += ak.x * x4.x + ak.y * x4.y + ak.z * x4.z + ak.w * x4.w;
                v[tt] += av.x * x4.x + av.y * x4.y + av.z * x4.z + av.w * x4.w;
            }
        }
        float s[10], e_[10];
        #pragma unroll
        for (int tt = 0; tt < 10; ++tt) s[tt] = act ? q[tt] * k[tt] : -1e30f;
        #pragma unroll
        for (int tt = 0; tt < 10; ++tt) {
            float m = s[tt];
            #pragma unroll
            for (int off = 1; off < 64; off <<= 1) m = fmaxf(m, __shfl_xor(m, off));
            if (lane == 0) wredM[wave][tt] = m;
        }
        __syncthreads();
        #pragma unroll
        for (int tt = 0; tt < 10; ++tt) {
            float mx = fmaxf(wredM[0][tt], wredM[1][tt]);
            e_[tt] = expf(s[tt] - mx);
        }
        #pragma unroll
        for (int tt = 0; tt < 10; ++tt) {
            float sm = e_[tt];
            #pragma unroll
            for (int off = 1; off < 64; off <<= 1) sm += __shfl_xor(sm, off);
            if (lane == 0) wredS[wave][tt] = sm;
        }
        __syncthreads();
        #pragma unroll
        for (int tt = 0; tt < 10; ++tt) {
            float sm = wredS[0][tt] + wredS[1][tt];
            acc += e_[tt] / sm * v[tt];
        }
    }
    if (act) tfeat[b * 1536 + stage * 768 + n * 96 + tid] = acc;
}

// ---------- cross-modal gated fusion + final logits ----------
__global__ void __launch_bounds__(128) k_final(const float* __restrict__ xgap,
    const float* __restrict__ outs, const float* __restrict__ afeat,
    const float* __restrict__ tfeat,
    const float* __restrict__ w_fa, const float* __restrict__ b_fa,
    const float* __restrict__ w_ft, const float* __restrict__ b_ft,
    const float* __restrict__ w_e, const float* __restrict__ b_e,
    float* __restrict__ out) {
    int b = blockIdx.x; int tid = threadIdx.x;
    __shared__ float xg[96], hv[100], st[100], sa[96], aat[96], atba[100];
    __shared__ float redm[2], reds[2];
    if (tid < 96) xg[tid] = xgap[b * 96 + tid];
    if (tid < 100) hv[tid] = outs[(size_t)(b * kT + kT - 1) * 100 + tid];
    __syncthreads();
    if (tid < 100) {
        float acc = b_fa[tid];
        const float* wr = w_fa + tid * 96;
        for (int c = 0; c < 96; ++c) acc += wr[c] * xg[c];
        st[tid] = acc;
    }
    if (tid < 96) {
        float acc = b_ft[tid];
        const float* wr = w_ft + tid * 100;
        for (int c = 0; c < 100; ++c) acc += wr[c] * hv[c];
        sa[tid] = acc;
    }
    __syncthreads();
    if (tid == 0) {
        float mxv = -1e30f; for (int i = 0; i < 100; ++i) mxv = fmaxf(mxv, st[i]);
        float s = 0.f; for (int i = 0; i < 100; ++i) s += expf(st[i] - mxv);
        redm[0] = mxv; reds[0] = s;
    }
    if (tid == 1) {
        float mxv = -1e30f; for (int i = 0; i < 96; ++i) mxv = fmaxf(mxv, sa[i]);
        float s = 0.f; for (int i = 0; i < 96; ++i) s += expf(sa[i] - mxv);
        redm[1] = mxv; reds[1] = s;
    }
    __syncthreads();
    if (tid < 100) atba[tid] = expf(st[tid] - redm[0]) / reds[0] * hv[tid];
    if (tid < 96)  aat[tid]  = expf(sa[tid] - redm[1]) / reds[1] * xg[tid];
    __syncthreads();
    float a0 = 0.f, a1 = 0.f, a2 = 0.f, a3 = 0.f;
    for (int col = tid; col < 3268; col += 128) {
        float f;
        if (col < 1536)      f = afeat[b * 1536 + col];
        else if (col < 3072) f = tfeat[b * 1536 + col - 1536];
        else if (col < 3168) f = aat[col - 3072];
        else                 f = atba[col - 3168];
        a0 += w_e[col] * f;            a1 += w_e[3268 + col] * f;
        a2 += w_e[2 * 3268 + col] * f; a3 += w_e[3 * 3268 + col] * f;
    }
    __shared__ float r4[4][128];
    r4[0][tid] = a0; r4[1][tid] = a1; r4[2][tid] = a2; r4[3][tid] = a3;
    __syncthreads();
    if (tid < 4) {
        float s = 0.f;
        for (int i = 0; i < 128; ++i) s += r4[tid][i];
        out[b * 4 + tid] = s + b_e[tid];
    }
}

// =====================================================================
extern "C" void kernel_launch(void* const* d_in, const int* in_sizes, int n_in,
                              void* d_out, int out_size, void* d_ws, size_t ws_size,
                              hipStream_t stream) {
    (void)in_sizes; (void)n_in; (void)out_size; (void)ws_size;
    const float* mfcc_t = (const float*)d_in[0];
    const float* mfcc_f = (const float*)d_in[1];
    const float* mfcc_c = (const float*)d_in[2];
    const int*   tokens = (const int*)d_in[3];
    const float *w1a = (const float*)d_in[5],  *b1a = (const float*)d_in[6],
                *g1a = (const float*)d_in[7],  *be1a = (const float*)d_in[8],
                *m1a = (const float*)d_in[9],  *v1a = (const float*)d_in[10];
    const float *w1b = (const float*)d_in[11], *b1b = (const float*)d_in[12],
                *g1b = (const float*)d_in[13], *be1b = (const float*)d_in[14],
                *m1b = (const float*)d_in[15], *v1b = (const float*)d_in[16];
    const float *w2 = (const float*)d_in[17], *b2 = (const float*)d_in[18],
                *g2 = (const float*)d_in[19], *be2 = (const float*)d_in[20],
                *m2 = (const float*)d_in[21], *v2 = (const float*)d_in[22];
    const float *w3 = (const float*)d_in[23], *b3 = (const float*)d_in[24],
                *g3 = (const float*)d_in[25], *be3 = (const float*)d_in[26],
                *m3 = (const float*)d_in[27], *v3 = (const float*)d_in[28];
    const float *w4 = (const float*)d_in[29], *b4 = (const float*)d_in[30],
                *g4 = (const float*)d_in[31], *be4 = (const float*)d_in[32],
                *m4 = (const float*)d_in[33], *v4 = (const float*)d_in[34];
    const float *wq_a1 = (const float*)d_in[35], *bq_a1 = (const float*)d_in[36],
                *wk_a1 = (const float*)d_in[37], *bk_a1 = (const float*)d_in[38],
                *wv_a1 = (const float*)d_in[39], *bv_a1 = (const float*)d_in[40];
    const float *wq_a2 = (const float*)d_in[41], *bq_a2 = (const float*)d_in[42],
                *wk_a2 = (const float*)d_in[43], *bk_a2 = (const float*)d_in[44],
                *wv_a2 = (const float*)d_in[45], *bv_a2 = (const float*)d_in[46];
    const float *emb  = (const float*)d_in[47];
    const float *w_ih = (const float*)d_in[48], *w_hh = (const float*)d_in[49],
                *b_ih = (const float*)d_in[50], *b_hh = (const float*)d_in[51];
    const float *wq_t1 = (const float*)d_in[52], *bq_t1 = (const float*)d_in[53],
                *wk_t1 = (const float*)d_in[54], *bk_t1 = (const float*)d_in[55],
                *wv_t1 = (const float*)d_in[56], *bv_t1 = (const float*)d_in[57];
    const float *wq_t2 = (const float*)d_in[58], *bq_t2 = (const float*)d_in[59],
                *wk_t2 = (const float*)d_in[60], *bk_t2 = (const float*)d_in[61],
                *wv_t2 = (const float*)d_in[62], *bv_t2 = (const float*)d_in[63];
    const float *w_fa = (const float*)d_in[64], *b_fa = (const float*)d_in[65],
                *w_ft = (const float*)d_in[66], *b_ft = (const float*)d_in[67],
                *w_e  = (const float*)d_in[68], *b_e  = (const float*)d_in[69];

    float* ws = (float*)d_ws;
    const size_t Z0 = 0;                 // xa|xb|xc -> c2 -> c3 -> x4
    const size_t Z1 = 22091776ull;       // x1 -> p2 -> p3 -> GI
    const size_t OUTS  = 34072576ull;    // conv-wT (early) then GRU outputs
    const size_t AFEAT = 34712576ull;
    const size_t TFEAT = 34909184ull;
    const size_t XGAP  = 35105792ull;
    const size_t WT    = 35118080ull;
    float* XA = ws + Z0;
    float* XB = ws + Z0 + 7827456ull;
    float* XC = ws + Z0 + 14959616ull;
    float* X1 = ws + Z1;
    float* C2 = ws + Z0;  float* P2 = ws + Z1;
    float* C3 = ws + Z0;  float* P3 = ws + Z1;
    float* X4 = ws + Z0;  float* GI = ws + Z1;
    float* outs  = ws + OUTS;
    float* afeat = ws + AFEAT;
    float* tfeat = ws + TFEAT;
    float* xgap  = ws + XGAP;
    float* wqa1t = ws + WT;
    float* wka1t = wqa1t + 73728; float* wva1t = wka1t + 73728;
    float* wqa2t = wva1t + 73728; float* wka2t = wqa2t + 73728; float* wva2t = wka2t + 73728;
    // conv weight transposes parked in the (still dead) GRU outs region
    float* wT2 = outs;            //  6,912
    float* wT3 = outs + 6912;     // 18,432
    float* wT4 = outs + 25344;    // 55,296

    // ----- all weight transposes in ONE launch -----
    TPack tp;
    tp.d[0] = {wq_a1, wqa1t, 96, 96, 73728};
    tp.d[1] = {wk_a1, wka1t, 96, 96, 73728};
    tp.d[2] = {wv_a1, wva1t, 96, 96, 73728};
    tp.d[3] = {wq_a2, wqa2t, 96, 96, 73728};
    tp.d[4] = {wk_a2, wka2t, 96, 96, 73728};
    tp.d[5] = {wv_a2, wva2t, 96, 96, 73728};
    tp.d[6] = {w2, wT2, 32, 216, 6912};
    tp.d[7] = {w3, wT3, 64, 288, 18432};
    tp.d[8] = {w4, wT4, 96, 576, 55296};
    k_transpose_pack<<<dim3(288, 9), 256, 0, stream>>>(tp);

    // ----- audio CNN stem (two-pass: conv1 x3 then resize+concat; R2-proven) -----
    k_conv1_bn_relu<<<30576, 256, 0, stream>>>(mfcc_t, w1a, b1a, g1a, be1a, m1a, v1a,
                                               XA, 200, 40, 196, 39, 5, 2, 7827456);
    k_conv1_bn_relu<<<27860, 256, 0, stream>>>(mfcc_f, w1b, b1b, g1b, be1b, m1b, v1b,
                                               XB, 200, 40, 199, 35, 2, 6, 7132160);
    k_conv1_bn_relu<<<27860, 256, 0, stream>>>(mfcc_c, w1b, b1b, g1b, be1b, m1b, v1b,
                                               XC, 200, 40, 199, 35, 2, 6, 7132160);
    k_resize_concat<<<46800, 256, 0, stream>>>(XA, XB, XC, X1, 11980800);
    k_conv3x3_tiled<24, 8, 25, 156, 9, 6><<<dim3(128, 3, 4), 256, 0, stream>>>(
        X1, wT2, b2, g2, be2, m2, v2, C2, 32);
    k_maxpool<<<14976, 256, 0, stream>>>(C2, P2, 32, 25, 156, 12, 78, 3833856);
    k_conv3x3_tiled<32, 8, 12, 78, 12, 4><<<dim3(128, 1, 8), 256, 0, stream>>>(
        P2, wT3, b3, g3, be3, m3, v3, C3, 64);
    k_maxpool<<<7488, 256, 0, stream>>>(C3, P3, 64, 12, 78, 6, 39, 1916928);
    k_conv3x3_tiled<64, 16, 6, 39, 6, 1><<<dim3(128, 1, 12), 256, 0, stream>>>(
        P3, wT4, b4, g4, be4, m4, v4, X4, 96);

    // ----- audio attention (+GAP folded in) -----
    k_audio_attn<<<dim3(kB, 8, 2), 128, 0, stream>>>(X4,
        wqa1t, bq_a1, wka1t, bk_a1, wva1t, bv_a1,
        wqa2t, bq_a2, wka2t, bk_a2, wva2t, bv_a2, afeat, xgap);

    // ----- text branch -----
    k_gi<<<kB * kT / 8, 320, 0, stream>>>(tokens, emb, w_ih, b_ih, GI);
    k_gru_all<<<kB, 320, 0, stream>>>(GI, w_hh, b_hh, outs);
    k_text_attn<<<dim3(kB, 2, 8), 128, 0, stream>>>(outs,
        wq_t1, bq_t1, wk_t1, bk_t1, wv_t1, bv_t1,
        wq_t2, bq_t2, wk_t2, bk_t2, wv_t2, bv_t2, tfeat);

    // ----- fusion + logits -----
    k_final<<<kB, 128, 0, stream>>>(xgap, outs, afeat, tfeat,
                                    w_fa, b_fa, w_ft, b_ft, w_e, b_e, (float*)d_out);
}

// Round 9
// 1712.249 us; speedup vs baseline: 1.0920x; 1.0401x over previous
//
#include <hip/hip_runtime.h>
#include <math.h>

// ---------------- constants ----------------
static constexpr int kB = 128;
static constexpr int kT = 50;

// ---------- packed transpose [N][O][C] -> [N][C][O], 9 segments, one launch ----------
struct TDesc { const float* src; float* dst; int O; int C; int total; };
struct TPack { TDesc d[9]; };
__global__ void k_transpose_pack(TPack p) {
    TDesc t = p.d[blockIdx.y];
    int idx = blockIdx.x * 256 + threadIdx.x;
    if (idx >= t.total) return;
    int o = idx % t.O; int r = idx / t.O; int c = r % t.C; int n = r / t.C;
    t.dst[idx] = t.src[((size_t)n * t.O + o) * t.C + c];
}

// ---------- fused stem: conv1{a,b,b} + BN + ReLU + bilinear resize + concat ----------
// Measured-good (R4/R5 totals 1698/1711 vs split-stem 1781).
__global__ void k_stem(const float* __restrict__ mt, const float* __restrict__ mf,
                       const float* __restrict__ mc,
                       const float* __restrict__ w1a, const float* __restrict__ b1a,
                       const float* __restrict__ g1a, const float* __restrict__ be1a,
                       const float* __restrict__ m1a, const float* __restrict__ v1a,
                       const float* __restrict__ w1b, const float* __restrict__ b1b,
                       const float* __restrict__ g1b, const float* __restrict__ be1b,
                       const float* __restrict__ m1b, const float* __restrict__ v1b,
                       float* __restrict__ out, int total) {
    int idx = blockIdx.x * blockDim.x + threadIdx.x;
    if (idx >= total) return;
    int ox = idx % 156; int t = idx / 156;
    int oy = t % 25; t /= 25;
    int ch = t % 24; int b = t / 24;
    int grp = ch >> 3, c = ch & 7;
    const float* src; int Hc, Wc;
    const float *wb, *cb, *g, *be, *m, *v;
    if (grp == 0) { src = mt; Hc = 196; Wc = 39; wb = w1a + c * 10;
                    cb = b1a; g = g1a; be = be1a; m = m1a; v = v1a; }
    else          { src = (grp == 1 ? mf : mc); Hc = 199; Wc = 35; wb = w1b + c * 12;
                    cb = b1b; g = g1b; be = be1b; m = m1b; v = v1b; }
    float s = g[c] * rsqrtf(v[c] + 1e-5f);
    float bias = (cb[c] - m[c]) * s + be[c];
    float sy = (oy + 0.5f) * ((float)Hc / 25.f) - 0.5f;
    float sx = (ox + 0.5f) * ((float)Wc / 156.f) - 0.5f;
    float fy0 = floorf(sy), fx0 = floorf(sx);
    float fy = sy - fy0, fx = sx - fx0;
    int y0 = (int)fy0, x0 = (int)fx0;
    int y0c = min(max(y0, 0), Hc - 1), y1c = min(max(y0 + 1, 0), Hc - 1);
    int x0c = min(max(x0, 0), Wc - 1), x1c = min(max(x0 + 1, 0), Wc - 1);
    const float* p = src + (size_t)b * 8000;   // 200*40
    float t00 = 0.f, t01 = 0.f, t10 = 0.f, t11 = 0.f;
    if (grp == 0) {
        #pragma unroll
        for (int ky = 0; ky < 5; ++ky)
            #pragma unroll
            for (int kx = 0; kx < 2; ++kx) {
                float wv = wb[ky * 2 + kx];
                t00 += p[(y0c + ky) * 40 + x0c + kx] * wv;
                t01 += p[(y0c + ky) * 40 + x1c + kx] * wv;
                t10 += p[(y1c + ky) * 40 + x0c + kx] * wv;
                t11 += p[(y1c + ky) * 40 + x1c + kx] * wv;
            }
    } else {
        #pragma unroll
        for (int ky = 0; ky < 2; ++ky)
            #pragma unroll
            for (int kx = 0; kx < 6; ++kx) {
                float wv = wb[ky * 6 + kx];
                t00 += p[(y0c + ky) * 40 + x0c + kx] * wv;
                t01 += p[(y0c + ky) * 40 + x1c + kx] * wv;
                t10 += p[(y1c + ky) * 40 + x0c + kx] * wv;
                t11 += p[(y1c + ky) * 40 + x1c + kx] * wv;
            }
    }
    float r00 = fmaxf(t00 * s + bias, 0.f), r01 = fmaxf(t01 * s + bias, 0.f);
    float r10 = fmaxf(t10 * s + bias, 0.f), r11 = fmaxf(t11 * s + bias, 0.f);
    out[idx] = r00 * (1.f - fy) * (1.f - fx) + r01 * (1.f - fy) * fx
             + r10 * fy * (1.f - fx) + r11 * fy * fx;
}

// ---------- LDS-tiled 3x3 conv, pad 1, fused BN(eval) + ReLU ----------
template<int CIN, int CI_T, int H, int W, int ROWS, int NPX>
__global__ void __launch_bounds__(256) k_conv3x3_tiled(
    const float* __restrict__ in, const float* __restrict__ wT,
    const float* __restrict__ cb, const float* __restrict__ g,
    const float* __restrict__ be, const float* __restrict__ m,
    const float* __restrict__ v, float* __restrict__ out, int COUT) {
    constexpr int WP = W + 2;
    constexpr int RP = ROWS + 2;
    constexpr int STAGE = CI_T * RP * WP;
    __shared__ float sx[STAGE];
    __shared__ float sw[CI_T * 9 * 8];
    const int b = blockIdx.x, rt = blockIdx.y, oc0 = blockIdx.z * 8;
    const int row0 = rt * ROWS;
    const int tid = threadIdx.x;

    int off[NPX]; bool val[NPX];
    #pragma unroll
    for (int j = 0; j < NPX; ++j) {
        int px = tid + j * 256;
        int oy = px / W, ox = px - oy * W;
        bool ok = (px < ROWS * W) && (row0 + oy < H);
        val[j] = ok;
        off[j] = ok ? (oy * WP + ox) : 0;
    }

    float acc[NPX][8];
    #pragma unroll
    for (int j = 0; j < NPX; ++j)
        #pragma unroll
        for (int o = 0; o < 8; ++o) acc[j][o] = 0.f;

    for (int c0 = 0; c0 < CIN; c0 += CI_T) {
        __syncthreads();
        for (int e = tid; e < STAGE; e += 256) {
            int ci = e / (RP * WP);
            int rem = e - ci * RP * WP;
            int r = rem / WP;
            int xx = rem - r * WP;
            int iy = row0 - 1 + r;
            int ix = xx - 1;
            float vv = 0.f;
            if (iy >= 0 && iy < H && ix >= 0 && ix < W)
                vv = in[((size_t)(b * CIN + c0 + ci) * H + iy) * W + ix];
            sx[e] = vv;
        }
        for (int e = tid; e < CI_T * 9 * 8; e += 256) {
            int rk = e >> 3;
            int o = e & 7;
            sw[e] = wT[((size_t)c0 * 9 + rk) * COUT + oc0 + o];
        }
        __syncthreads();
        #pragma unroll 1
        for (int cl = 0; cl < CI_T; ++cl) {
            const float* sxc = sx + cl * RP * WP;
            #pragma unroll
            for (int k = 0; k < 9; ++k) {
                const int ky = k / 3, kx = k % 3;
                const float4 wa = *(const float4*)(sw + (cl * 9 + k) * 8);
                const float4 wb = *(const float4*)(sw + (cl * 9 + k) * 8 + 4);
                #pragma unroll
                for (int j = 0; j < NPX; ++j) {
                    float xv = sxc[off[j] + ky * WP + kx];
                    acc[j][0] += xv * wa.x; acc[j][1] += xv * wa.y;
                    acc[j][2] += xv * wa.z; acc[j][3] += xv * wa.w;
                    acc[j][4] += xv * wb.x; acc[j][5] += xv * wb.y;
                    acc[j][6] += xv * wb.z; acc[j][7] += xv * wb.w;
                }
            }
        }
    }
    float sc[8], bi[8];
    #pragma unroll
    for (int o = 0; o < 8; ++o) {
        float s = g[oc0 + o] * rsqrtf(v[oc0 + o] + 1e-5f);
        sc[o] = s; bi[o] = (cb[oc0 + o] - m[oc0 + o]) * s + be[oc0 + o];
    }
    #pragma unroll
    for (int j = 0; j < NPX; ++j) if (val[j]) {
        int px = tid + j * 256;
        int oy = row0 + px / W, ox = px % W;
        #pragma unroll
        for (int o = 0; o < 8; ++o)
            out[((size_t)(b * COUT + oc0 + o) * H + oy) * W + ox] =
                fmaxf(acc[j][o] * sc[o] + bi[o], 0.f);
    }
}

// ---------- 2x2 maxpool stride 2 (VALID) ----------
__global__ void k_maxpool(const float* __restrict__ in, float* __restrict__ out,
                          int C, int Hin, int Win, int Hout, int Wout, int total) {
    int idx = blockIdx.x * blockDim.x + threadIdx.x;
    if (idx >= total) return;
    int ox = idx % Wout; int t = idx / Wout;
    int oy = t % Hout; t /= Hout;
    int c = t % C; int b = t / C;
    const float* p = in + ((size_t)(b * C + c) * Hin + 2 * oy) * Win + 2 * ox;
    float m0 = fmaxf(p[0], p[1]);
    float m1 = fmaxf(p[Win], p[Win + 1]);
    out[idx] = fmaxf(m0, m1);
}

// ---------- fused audio attention: TWO HEADS per block, 100% lane utilization ----------
// 192 threads = 3 waves; tid/96 = head within pair, tid%96 = o. All lanes active
// in the QKV loop. xt tile staged ONCE per head-pair. Inner structure = R5's
// measured-best (stride-28 xt float4 reads, stride-27 sb, bias-init, 2-stage reduce).
// grid (b=128, npair=4, stage=2) = 1024 blocks = exactly 4/CU.
__global__ void __launch_bounds__(192) k_audio_attn(
    const float* __restrict__ x,
    const float* __restrict__ wq1, const float* __restrict__ bq1,
    const float* __restrict__ wk1, const float* __restrict__ bk1,
    const float* __restrict__ wv1, const float* __restrict__ bv1,
    const float* __restrict__ wq2, const float* __restrict__ bq2,
    const float* __restrict__ wk2, const float* __restrict__ bk2,
    const float* __restrict__ wv2, const float* __restrict__ bv2,
    float* __restrict__ afeat, float* __restrict__ xgap) {
    int b = blockIdx.x, npair = blockIdx.y, stage = blockIdx.z;
    const float* wq = stage ? wq2 : wq1; const float* bq = stage ? bq2 : bq1;
    const float* wk = stage ? wk2 : wk1; const float* bk = stage ? bk2 : bk1;
    const float* wv = stage ? wv2 : wv1; const float* bv = stage ? bv2 : bv1;
    __shared__ float xt[96 * 28];            // 10.5 KB, shared by both heads
    __shared__ float sb[2][96 * 27];         // 20.25 KB
    __shared__ float pmax[2][3][26], psum[2][3][26];
    __shared__ float mx[2][26], sm[2][26];
    int tid = threadIdx.x;
    int h = tid / 96;        // head within pair (all 192 threads active)
    int o = tid - h * 96;
    int n = npair * 2 + h;
    float bqv = bq[n * 96 + o];
    float bkv = bk[n * 96 + o];
    float bvv = bv[n * 96 + o];
    const float* wqb = wq + n * 9216 + o;    // [c][o] layout -> wqb[c*96]
    const float* wkb = wk + n * 9216 + o;
    const float* wvb = wv + n * 9216 + o;
    const bool do_gap = (npair == 0 && stage == 0 && h == 0);
    float accO = 0.f, xsum = 0.f;
    const float* xb = x + (size_t)b * 96 * 234;
    for (int tile = 0; tile < 9; ++tile) {
        int p0 = tile * 26;
        __syncthreads();
        for (int e = tid; e < 2496; e += 192) {
            int c = e / 26, pp = e - c * 26;
            xt[c * 28 + pp] = xb[c * 234 + p0 + pp];
        }
        __syncthreads();
        if (do_gap) {
            const float* xr = xt + o * 28;
            #pragma unroll
            for (int p = 0; p < 26; ++p) xsum += xr[p];
        }
        float aq[26], ak[26], av[26];
        #pragma unroll
        for (int p = 0; p < 26; ++p) { aq[p] = bqv; ak[p] = bkv; av[p] = bvv; }
        for (int c = 0; c < 96; ++c) {
            float wqv = wqb[c * 96], wkv = wkb[c * 96], wvv2 = wvb[c * 96];
            const float* xr = xt + c * 28;
            #pragma unroll
            for (int q4 = 0; q4 < 6; ++q4) {
                float4 x4 = *(const float4*)(xr + q4 * 4);
                int p = q4 * 4;
                aq[p]   += wqv * x4.x; ak[p]   += wkv * x4.x; av[p]   += wvv2 * x4.x;
                aq[p+1] += wqv * x4.y; ak[p+1] += wkv * x4.y; av[p+1] += wvv2 * x4.y;
                aq[p+2] += wqv * x4.z; ak[p+2] += wkv * x4.z; av[p+2] += wvv2 * x4.z;
                aq[p+3] += wqv * x4.w; ak[p+3] += wkv * x4.w; av[p+3] += wvv2 * x4.w;
            }
            float2 x2 = *(const float2*)(xr + 24);
            aq[24] += wqv * x2.x; ak[24] += wkv * x2.x; av[24] += wvv2 * x2.x;
            aq[25] += wqv * x2.y; ak[25] += wkv * x2.y; av[25] += wvv2 * x2.y;
        }
        #pragma unroll
        for (int p = 0; p < 26; ++p)
            sb[h][o * 27 + p] = aq[p] * ak[p];
        __syncthreads();
        // per-head two-stage max over o (96 = 3 chunks of 32), 156 threads
        if (tid < 156) {
            int hh = tid / 78; int w = tid - hh * 78;
            int p = w % 26, ch = w / 26;
            int o0 = ch * 32;
            float m_ = -1e30f;
            for (int q = 0; q < 32; ++q) m_ = fmaxf(m_, sb[hh][(o0 + q) * 27 + p]);
            pmax[hh][ch][p] = m_;
        }
        __syncthreads();
        if (tid < 52) {
            int hh = tid / 26, p = tid - hh * 26;
            mx[hh][p] = fmaxf(fmaxf(pmax[hh][0][p], pmax[hh][1][p]), pmax[hh][2][p]);
        }
        __syncthreads();
        if (tid < 156) {
            int hh = tid / 78; int w = tid - hh * 78;
            int p = w % 26, ch = w / 26;
            int o0 = ch * 32;
            float mv = mx[hh][p];
            float s_ = 0.f;
            for (int q = 0; q < 32; ++q) s_ += __expf(sb[hh][(o0 + q) * 27 + p] - mv);
            psum[hh][ch][p] = s_;
        }
        __syncthreads();
        if (tid < 52) {
            int hh = tid / 26, p = tid - hh * 26;
            sm[hh][p] = psum[hh][0][p] + psum[hh][1][p] + psum[hh][2][p];
        }
        __syncthreads();
        #pragma unroll
        for (int p = 0; p < 26; ++p)
            accO += __expf(sb[h][o * 27 + p] - mx[h][p]) / sm[h][p] * av[p];
    }
    afeat[b * 1536 + n * 192 + stage * 96 + o] = accO * (1.f / 234.f);
    if (do_gap) xgap[b * 96 + o] = xsum * (1.f / 234.f);
}

// ---------- embedding lookup + input-side GRU GEMM, 8 rows/block ----------
__global__ void __launch_bounds__(320) k_gi(const int* __restrict__ tokens,
        const float* __restrict__ emb, const float* __restrict__ w_ih,
        const float* __restrict__ b_ih, float* __restrict__ GI) {
    int r0 = blockIdx.x * 8;
    int tid = threadIdx.x;
    __shared__ float er[8][200];
    for (int e = tid; e < 1600; e += 320) {
        int r = e / 200, c = e - r * 200;
        er[r][c] = emb[(size_t)tokens[r0 + r] * 200 + c];
    }
    __syncthreads();
    if (tid < 300) {
        float acc[8];
        float bv = b_ih[tid];
        #pragma unroll
        for (int r = 0; r < 8; ++r) acc[r] = bv;
        for (int k4 = 0; k4 < 50; ++k4) {
            float4 w4 = *(const float4*)(w_ih + (size_t)tid * 200 + k4 * 4);
            #pragma unroll
            for (int r = 0; r < 8; ++r) {
                float4 x4 = *(const float4*)&er[r][k4 * 4];
                acc[r] += w4.x * x4.x + w4.y * x4.y + w4.z * x4.z + w4.w * x4.w;
            }
        }
        #pragma unroll
        for (int r = 0; r < 8; ++r)
            GI[(size_t)(r0 + r) * 300 + tid] = acc[r];
    }
}

// ---------- whole GRU recurrence in ONE kernel (one block per batch row) ----------
__global__ void __launch_bounds__(320) k_gru_all(const float* __restrict__ GI,
        const float* __restrict__ w_hh, const float* __restrict__ b_hh,
        float* __restrict__ outs) {
    int b = blockIdx.x, tid = threadIdx.x;
    __shared__ float hs[100];
    __shared__ float gH[300];
    float4 wreg[25];
    float bias = 0.f;
    if (tid < 300) {
        bias = b_hh[tid];
        #pragma unroll
        for (int k4 = 0; k4 < 25; ++k4)
            wreg[k4] = *(const float4*)(w_hh + (size_t)tid * 100 + k4 * 4);
    }
    if (tid < 100) hs[tid] = 0.f;
    __syncthreads();
    for (int t = 0; t < kT; ++t) {
        if (tid < 300) {
            float gh = bias;
            #pragma unroll
            for (int k4 = 0; k4 < 25; ++k4) {
                float4 h4 = *(const float4*)&hs[k4 * 4];
                gh += wreg[k4].x * h4.x + wreg[k4].y * h4.y
                    + wreg[k4].z * h4.z + wreg[k4].w * h4.w;
            }
            gH[tid] = gh;
        }
        __syncthreads();
        if (tid < 100) {
            const float* gi = GI + ((size_t)b * kT + t) * 300;
            float r = 1.f / (1.f + expf(-(gi[tid] + gH[tid])));
            float z = 1.f / (1.f + expf(-(gi[100 + tid] + gH[100 + tid])));
            float nn = tanhf(gi[200 + tid] + r * gH[200 + tid]);
            float h2 = (1.f - z) * nn + z * hs[tid];
            hs[tid] = h2;
            outs[((size_t)b * kT + t) * 100 + tid] = h2;
        }
        __syncthreads();
    }
}

// ---------- fused text attention (both stages), t-tiled, shuffle softmax ----------
__global__ void __launch_bounds__(128) k_text_attn(const float* __restrict__ outs,
    const float* __restrict__ wq1, const float* __restrict__ bq1,
    const float* __restrict__ wk1, const float* __restrict__ bk1,
    const float* __restrict__ wv1, const float* __restrict__ bv1,
    const float* __restrict__ wq2, const float* __restrict__ bq2,
    const float* __restrict__ wk2, const float* __restrict__ bk2,
    const float* __restrict__ wv2, const float* __restrict__ bv2,
    float* __restrict__ tfeat) {
    int b = blockIdx.x, stage = blockIdx.y, n = blockIdx.z;
    const float* wq = stage ? wq2 : wq1; const float* bq = stage ? bq2 : bq1;
    const float* wk = stage ? wk2 : wk1; const float* bk = stage ? bk2 : bk1;
    const float* wv = stage ? wv2 : wv1; const float* bv = stage ? bv2 : bv1;
    int tid = threadIdx.x;
    bool act = tid < 96;
    int oo = act ? tid : 0;
    const float* wqr = wq + ((size_t)n * 96 + oo) * 100;
    const float* wkr = wk + ((size_t)n * 96 + oo) * 100;
    const float* wvr = wv + ((size_t)n * 96 + oo) * 100;
    float bqv = act ? bq[n * 96 + tid] : 0.f;
    float bkv = act ? bk[n * 96 + tid] : 0.f;
    float bvv = act ? bv[n * 96 + tid] : 0.f;
    __shared__ float rows[10][100];
    __shared__ float wredM[2][10], wredS[2][10];
    float acc = 0.f;
    int wave = tid >> 6, lane = tid & 63;
    for (int tile = 0; tile < 5; ++tile) {
        int t0 = tile * 10;
        __syncthreads();
        for (int e = tid; e < 1000; e += 128) {
            int tt = e / 100, c = e - tt * 100;
            rows[tt][c] = outs[((size_t)b * kT + t0 + tt) * 100 + c];
        }
        __syncthreads();
        float q[10], k[10], v[10];
        #pragma unroll
        for (int tt = 0; tt < 10; ++tt) { q[tt] = bqv; k[tt] = bkv; v[tt] = bvv; }
        for (int c4 = 0; c4 < 25; ++c4) {
            float4 aq = *(const float4*)(wqr + c4 * 4);
            float4 ak = *(const float4*)(wkr + c4 * 4);
            float4 av = *(const float4*)(wvr + c4 * 4);
            #pragma unroll
            for (int tt = 0; tt < 10; ++tt) {
                float4 x4 = *(const float4*)&rows[tt][c4 * 4];
                q[tt] += aq.x * x4.x + aq.y * x4.y + aq.z * x4.z + aq.w * x4.w;
                k[tt] += ak.x * x4.x + ak.y * x4.y + ak.z * x4.z + ak.w * x4.w;
                v[tt] += av.x * x4.x + av.y * x4.y + av.z * x4.z + av.w * x4.w;
            }
        }
        float s[10], e_[10];
        #pragma unroll
        for (int tt = 0; tt < 10; ++tt) s[tt] = act ? q[tt] * k[tt] : -1e30f;
        #pragma unroll
        for (int tt = 0; tt < 10; ++tt) {
            float m = s[tt];
            #pragma unroll
            for (int off = 1; off < 64; off <<= 1) m = fmaxf(m, __shfl_xor(m, off));
            if (lane == 0) wredM[wave][tt] = m;
        }
        __syncthreads();
        #pragma unroll
        for (int tt = 0; tt < 10; ++tt) {
            float mx = fmaxf(wredM[0][tt], wredM[1][tt]);
            e_[tt] = expf(s[tt] - mx);
        }
        #pragma unroll
        for (int tt = 0; tt < 10; ++tt) {
            float sm = e_[tt];
            #pragma unroll
            for (int off = 1; off < 64; off <<= 1) sm += __shfl_xor(sm, off);
            if (lane == 0) wredS[wave][tt] = sm;
        }
        __syncthreads();
        #pragma unroll
        for (int tt = 0; tt < 10; ++tt) {
            float sm = wredS[0][tt] + wredS[1][tt];
            acc += e_[tt] / sm * v[tt];
        }
    }
    if (act) tfeat[b * 1536 + stage * 768 + n * 96 + tid] = acc;
}

// ---------- cross-modal gated fusion + final logits ----------
__global__ void __launch_bounds__(128) k_final(const float* __restrict__ xgap,
    const float* __restrict__ outs, const float* __restrict__ afeat,
    const float* __restrict__ tfeat,
    const float* __restrict__ w_fa, const float* __restrict__ b_fa,
    const float* __restrict__ w_ft, const float* __restrict__ b_ft,
    const float* __restrict__ w_e, const float* __restrict__ b_e,
    float* __restrict__ out) {
    int b = blockIdx.x; int tid = threadIdx.x;
    __shared__ float xg[96], hv[100], st[100], sa[96], aat[96], atba[100];
    __shared__ float redm[2], reds[2];
    if (tid < 96) xg[tid] = xgap[b * 96 + tid];
    if (tid < 100) hv[tid] = outs[(size_t)(b * kT + kT - 1) * 100 + tid];
    __syncthreads();
    if (tid < 100) {
        float acc = b_fa[tid];
        const float* wr = w_fa + tid * 96;
        for (int c = 0; c < 96; ++c) acc += wr[c] * xg[c];
        st[tid] = acc;
    }
    if (tid < 96) {
        float acc = b_ft[tid];
        const float* wr = w_ft + tid * 100;
        for (int c = 0; c < 100; ++c) acc += wr[c] * hv[c];
        sa[tid] = acc;
    }
    __syncthreads();
    if (tid == 0) {
        float mxv = -1e30f; for (int i = 0; i < 100; ++i) mxv = fmaxf(mxv, st[i]);
        float s = 0.f; for (int i = 0; i < 100; ++i) s += expf(st[i] - mxv);
        redm[0] = mxv; reds[0] = s;
    }
    if (tid == 1) {
        float mxv = -1e30f; for (int i = 0; i < 96; ++i) mxv = fmaxf(mxv, sa[i]);
        float s = 0.f; for (int i = 0; i < 96; ++i) s += expf(sa[i] - mxv);
        redm[1] = mxv; reds[1] = s;
    }
    __syncthreads();
    if (tid < 100) atba[tid] = expf(st[tid] - redm[0]) / reds[0] * hv[tid];
    if (tid < 96)  aat[tid]  = expf(sa[tid] - redm[1]) / reds[1] * xg[tid];
    __syncthreads();
    float a0 = 0.f, a1 = 0.f, a2 = 0.f, a3 = 0.f;
    for (int col = tid; col < 3268; col += 128) {
        float f;
        if (col < 1536)      f = afeat[b * 1536 + col];
        else if (col < 3072) f = tfeat[b * 1536 + col - 1536];
        else if (col < 3168) f = aat[col - 3072];
        else                 f = atba[col - 3168];
        a0 += w_e[col] * f;            a1 += w_e[3268 + col] * f;
        a2 += w_e[2 * 3268 + col] * f; a3 += w_e[3 * 3268 + col] * f;
    }
    __shared__ float r4[4][128];
    r4[0][tid] = a0; r4[1][tid] = a1; r4[2][tid] = a2; r4[3][tid] = a3;
    __syncthreads();
    if (tid < 4) {
        float s = 0.f;
        for (int i = 0; i < 128; ++i) s += r4[tid][i];
        out[b * 4 + tid] = s + b_e[tid];
    }
}

// =====================================================================
extern "C" void kernel_launch(void* const* d_in, const int* in_sizes, int n_in,
                              void* d_out, int out_size, void* d_ws, size_t ws_size,
                              hipStream_t stream) {
    (void)in_sizes; (void)n_in; (void)out_size; (void)ws_size;
    const float* mfcc_t = (const float*)d_in[0];
    const float* mfcc_f = (const float*)d_in[1];
    const float* mfcc_c = (const float*)d_in[2];
    const int*   tokens = (const int*)d_in[3];
    const float *w1a = (const float*)d_in[5],  *b1a = (const float*)d_in[6],
                *g1a = (const float*)d_in[7],  *be1a = (const float*)d_in[8],
                *m1a = (const float*)d_in[9],  *v1a = (const float*)d_in[10];
    const float *w1b = (const float*)d_in[11], *b1b = (const float*)d_in[12],
                *g1b = (const float*)d_in[13], *be1b = (const float*)d_in[14],
                *m1b = (const float*)d_in[15], *v1b = (const float*)d_in[16];
    const float *w2 = (const float*)d_in[17], *b2 = (const float*)d_in[18],
                *g2 = (const float*)d_in[19], *be2 = (const float*)d_in[20],
                *m2 = (const float*)d_in[21], *v2 = (const float*)d_in[22];
    const float *w3 = (const float*)d_in[23], *b3 = (const float*)d_in[24],
                *g3 = (const float*)d_in[25], *be3 = (const float*)d_in[26],
                *m3 = (const float*)d_in[27], *v3 = (const float*)d_in[28];
    const float *w4 = (const float*)d_in[29], *b4 = (const float*)d_in[30],
                *g4 = (const float*)d_in[31], *be4 = (const float*)d_in[32],
                *m4 = (const float*)d_in[33], *v4 = (const float*)d_in[34];
    const float *wq_a1 = (const float*)d_in[35], *bq_a1 = (const float*)d_in[36],
                *wk_a1 = (const float*)d_in[37], *bk_a1 = (const float*)d_in[38],
                *wv_a1 = (const float*)d_in[39], *bv_a1 = (const float*)d_in[40];
    const float *wq_a2 = (const float*)d_in[41], *bq_a2 = (const float*)d_in[42],
                *wk_a2 = (const float*)d_in[43], *bk_a2 = (const float*)d_in[44],
                *wv_a2 = (const float*)d_in[45], *bv_a2 = (const float*)d_in[46];
    const float *emb  = (const float*)d_in[47];
    const float *w_ih = (const float*)d_in[48], *w_hh = (const float*)d_in[49],
                *b_ih = (const float*)d_in[50], *b_hh = (const float*)d_in[51];
    const float *wq_t1 = (const float*)d_in[52], *bq_t1 = (const float*)d_in[53],
                *wk_t1 = (const float*)d_in[54], *bk_t1 = (const float*)d_in[55],
                *wv_t1 = (const float*)d_in[56], *bv_t1 = (const float*)d_in[57];
    const float *wq_t2 = (const float*)d_in[58], *bq_t2 = (const float*)d_in[59],
                *wk_t2 = (const float*)d_in[60], *bk_t2 = (const float*)d_in[61],
                *wv_t2 = (const float*)d_in[62], *bv_t2 = (const float*)d_in[63];
    const float *w_fa = (const float*)d_in[64], *b_fa = (const float*)d_in[65],
                *w_ft = (const float*)d_in[66], *b_ft = (const float*)d_in[67],
                *w_e  = (const float*)d_in[68], *b_e  = (const float*)d_in[69];

    float* ws = (float*)d_ws;
    const size_t Z0 = 0;                 // c2 -> c3 -> x4
    const size_t Z1 = 22091776ull;       // x1 -> p2 -> p3 -> GI
    const size_t OUTS  = 34072576ull;    // conv-wT (early) then GRU outputs
    const size_t AFEAT = 34712576ull;
    const size_t TFEAT = 34909184ull;
    const size_t XGAP  = 35105792ull;
    const size_t WT    = 35118080ull;
    float* X1 = ws + Z1;
    float* C2 = ws + Z0;  float* P2 = ws + Z1;
    float* C3 = ws + Z0;  float* P3 = ws + Z1;
    float* X4 = ws + Z0;  float* GI = ws + Z1;
    float* outs  = ws + OUTS;
    float* afeat = ws + AFEAT;
    float* tfeat = ws + TFEAT;
    float* xgap  = ws + XGAP;
    float* wqa1t = ws + WT;
    float* wka1t = wqa1t + 73728; float* wva1t = wka1t + 73728;
    float* wqa2t = wva1t + 73728; float* wka2t = wqa2t + 73728; float* wva2t = wka2t + 73728;
    // conv weight transposes parked in the (still dead) GRU outs region
    float* wT2 = outs;            //  6,912
    float* wT3 = outs + 6912;     // 18,432
    float* wT4 = outs + 25344;    // 55,296

    // ----- all weight transposes in ONE launch -----
    TPack tp;
    tp.d[0] = {wq_a1, wqa1t, 96, 96, 73728};
    tp.d[1] = {wk_a1, wka1t, 96, 96, 73728};
    tp.d[2] = {wv_a1, wva1t, 96, 96, 73728};
    tp.d[3] = {wq_a2, wqa2t, 96, 96, 73728};
    tp.d[4] = {wk_a2, wka2t, 96, 96, 73728};
    tp.d[5] = {wv_a2, wva2t, 96, 96, 73728};
    tp.d[6] = {w2, wT2, 32, 216, 6912};
    tp.d[7] = {w3, wT3, 64, 288, 18432};
    tp.d[8] = {w4, wT4, 96, 576, 55296};
    k_transpose_pack<<<dim3(288, 9), 256, 0, stream>>>(tp);

    // ----- fused stem (conv1 x3 + BN + ReLU + resize + concat; R4/R5-proven) -----
    k_stem<<<46800, 256, 0, stream>>>(mfcc_t, mfcc_f, mfcc_c,
        w1a, b1a, g1a, be1a, m1a, v1a,
        w1b, b1b, g1b, be1b, m1b, v1b, X1, 11980800);
    k_conv3x3_tiled<24, 8, 25, 156, 9, 6><<<dim3(128, 3, 4), 256, 0, stream>>>(
        X1, wT2, b2, g2, be2, m2, v2, C2, 32);
    k_maxpool<<<14976, 256, 0, stream>>>(C2, P2, 32, 25, 156, 12, 78, 3833856);
    k_conv3x3_tiled<32, 8, 12, 78, 12, 4><<<dim3(128, 1, 8), 256, 0, stream>>>(
        P2, wT3, b3, g3, be3, m3, v3, C3, 64);
    k_maxpool<<<7488, 256, 0, stream>>>(C3, P3, 64, 12, 78, 6, 39, 1916928);
    k_conv3x3_tiled<64, 16, 6, 39, 6, 1><<<dim3(128, 1, 12), 256, 0, stream>>>(
        P3, wT4, b4, g4, be4, m4, v4, X4, 96);

    // ----- audio attention (+GAP folded in): 2 heads/block, 1024 blocks -----
    k_audio_attn<<<dim3(kB, 4, 2), 192, 0, stream>>>(X4,
        wqa1t, bq_a1, wka1t, bk_a1, wva1t, bv_a1,
        wqa2t, bq_a2, wka2t, bk_a2, wva2t, bv_a2, afeat, xgap);

    // ----- text branch -----
    k_gi<<<kB * kT / 8, 320, 0, stream>>>(tokens, emb, w_ih, b_ih, GI);
    k_gru_all<<<kB, 320, 0, stream>>>(GI, w_hh, b_hh, outs);
    k_text_attn<<<dim3(kB, 2, 8), 128, 0, stream>>>(outs,
        wq_t1, bq_t1, wk_t1, bk_t1, wv_t1, bv_t1,
        wq_t2, bq_t2, wk_t2, bk_t2, wv_t2, bv_t2, tfeat);

    // ----- fusion + logits -----
    k_final<<<kB, 128, 0, stream>>>(xgap, outs, afeat, tfeat,
                                    w_fa, b_fa, w_ft, b_ft, w_e, b_e, (float*)d_out);
}

// Round 10
// 1669.674 us; speedup vs baseline: 1.1198x; 1.0255x over previous
//
#include <hip/hip_runtime.h>
#include <math.h>

// ---------------- constants ----------------
static constexpr int kB = 128;
static constexpr int kT = 50;

// ---------- packed transpose [N][O][C] -> [N][C][O], 9 segments, one launch ----------
struct TDesc { const float* src; float* dst; int O; int C; int total; };
struct TPack { TDesc d[9]; };
__global__ void k_transpose_pack(TPack p) {
    TDesc t = p.d[blockIdx.y];
    int idx = blockIdx.x * 256 + threadIdx.x;
    if (idx >= t.total) return;
    int o = idx % t.O; int r = idx / t.O; int c = r % t.C; int n = r / t.C;
    t.dst[idx] = t.src[((size_t)n * t.O + o) * t.C + c];
}

// ---------- fused stem: conv1{a,b,b} + BN + ReLU + bilinear resize + concat ----------
// Register-window version: the 4 bilinear taps' conv windows overlap; load the
// UNION window (6x3 grp0 / 3x7 grpB = 18/21 loads vs 40/48) once into registers,
// compute 4 interior-style sums, fix edge clamps via exact selects
// (x1c==x0c => t01==t00 identically, etc.).
__global__ void k_stem(const float* __restrict__ mt, const float* __restrict__ mf,
                       const float* __restrict__ mc,
                       const float* __restrict__ w1a, const float* __restrict__ b1a,
                       const float* __restrict__ g1a, const float* __restrict__ be1a,
                       const float* __restrict__ m1a, const float* __restrict__ v1a,
                       const float* __restrict__ w1b, const float* __restrict__ b1b,
                       const float* __restrict__ g1b, const float* __restrict__ be1b,
                       const float* __restrict__ m1b, const float* __restrict__ v1b,
                       float* __restrict__ out, int total) {
    int idx = blockIdx.x * blockDim.x + threadIdx.x;
    if (idx >= total) return;
    int ox = idx % 156; int t = idx / 156;
    int oy = t % 25; t /= 25;
    int ch = t % 24; int b = t / 24;
    int grp = ch >> 3, c = ch & 7;
    const float* src; int Hc, Wc;
    const float *wb, *cb, *g, *be, *m, *v;
    if (grp == 0) { src = mt; Hc = 196; Wc = 39; wb = w1a + c * 10;
                    cb = b1a; g = g1a; be = be1a; m = m1a; v = v1a; }
    else          { src = (grp == 1 ? mf : mc); Hc = 199; Wc = 35; wb = w1b + c * 12;
                    cb = b1b; g = g1b; be = be1b; m = m1b; v = v1b; }
    float s = g[c] * rsqrtf(v[c] + 1e-5f);
    float bias = (cb[c] - m[c]) * s + be[c];
    float sy = (oy + 0.5f) * ((float)Hc / 25.f) - 0.5f;
    float sx = (ox + 0.5f) * ((float)Wc / 156.f) - 0.5f;
    float fy0 = floorf(sy), fx0 = floorf(sx);
    float fy = sy - fy0, fx = sx - fx0;
    int y0 = (int)fy0, x0 = (int)fx0;
    int y0c = min(max(y0, 0), Hc - 1), y1c = min(max(y0 + 1, 0), Hc - 1);
    int x0c = min(max(x0, 0), Wc - 1), x1c = min(max(x0 + 1, 0), Wc - 1);
    bool xs = (x1c == x0c), ys = (y1c == y0c);
    const float* p = src + (size_t)b * 8000;   // input 200 x 40
    float t00, t01, t10, t11;
    if (grp == 0) {
        // KH=5 KW=2: union window 6 rows x 3 cols
        float W[6][3];
        #pragma unroll
        for (int r = 0; r < 6; ++r) {
            int rr = min(y0c + r, 199);
            #pragma unroll
            for (int cc = 0; cc < 3; ++cc)
                W[r][cc] = p[rr * 40 + min(x0c + cc, 39)];
        }
        float a00 = 0.f, a01 = 0.f, a10 = 0.f, a11 = 0.f;
        #pragma unroll
        for (int ky = 0; ky < 5; ++ky)
            #pragma unroll
            for (int kx = 0; kx < 2; ++kx) {
                float wv = wb[ky * 2 + kx];
                a00 += W[ky][kx] * wv;     a01 += W[ky][kx + 1] * wv;
                a10 += W[ky + 1][kx] * wv; a11 += W[ky + 1][kx + 1] * wv;
            }
        t00 = a00;
        t01 = xs ? a00 : a01;
        t10 = ys ? a00 : a10;
        t11 = xs ? (ys ? a00 : a10) : (ys ? a01 : a11);
    } else {
        // KH=2 KW=6: union window 3 rows x 7 cols
        float W[3][7];
        #pragma unroll
        for (int r = 0; r < 3; ++r) {
            int rr = min(y0c + r, 199);
            #pragma unroll
            for (int cc = 0; cc < 7; ++cc)
                W[r][cc] = p[rr * 40 + min(x0c + cc, 39)];
        }
        float a00 = 0.f, a01 = 0.f, a10 = 0.f, a11 = 0.f;
        #pragma unroll
        for (int ky = 0; ky < 2; ++ky)
            #pragma unroll
            for (int kx = 0; kx < 6; ++kx) {
                float wv = wb[ky * 6 + kx];
                a00 += W[ky][kx] * wv;     a01 += W[ky][kx + 1] * wv;
                a10 += W[ky + 1][kx] * wv; a11 += W[ky + 1][kx + 1] * wv;
            }
        t00 = a00;
        t01 = xs ? a00 : a01;
        t10 = ys ? a00 : a10;
        t11 = xs ? (ys ? a00 : a10) : (ys ? a01 : a11);
    }
    float r00 = fmaxf(t00 * s + bias, 0.f), r01 = fmaxf(t01 * s + bias, 0.f);
    float r10 = fmaxf(t10 * s + bias, 0.f), r11 = fmaxf(t11 * s + bias, 0.f);
    out[idx] = r00 * (1.f - fy) * (1.f - fx) + r01 * (1.f - fy) * fx
             + r10 * fy * (1.f - fx) + r11 * fy * fx;
}

// ---------- LDS-tiled 3x3 conv, pad 1, fused BN(eval) + ReLU ----------
template<int CIN, int CI_T, int H, int W, int ROWS, int NPX>
__global__ void __launch_bounds__(256) k_conv3x3_tiled(
    const float* __restrict__ in, const float* __restrict__ wT,
    const float* __restrict__ cb, const float* __restrict__ g,
    const float* __restrict__ be, const float* __restrict__ m,
    const float* __restrict__ v, float* __restrict__ out, int COUT) {
    constexpr int WP = W + 2;
    constexpr int RP = ROWS + 2;
    constexpr int STAGE = CI_T * RP * WP;
    __shared__ float sx[STAGE];
    __shared__ float sw[CI_T * 9 * 8];
    const int b = blockIdx.x, rt = blockIdx.y, oc0 = blockIdx.z * 8;
    const int row0 = rt * ROWS;
    const int tid = threadIdx.x;

    int off[NPX]; bool val[NPX];
    #pragma unroll
    for (int j = 0; j < NPX; ++j) {
        int px = tid + j * 256;
        int oy = px / W, ox = px - oy * W;
        bool ok = (px < ROWS * W) && (row0 + oy < H);
        val[j] = ok;
        off[j] = ok ? (oy * WP + ox) : 0;
    }

    float acc[NPX][8];
    #pragma unroll
    for (int j = 0; j < NPX; ++j)
        #pragma unroll
        for (int o = 0; o < 8; ++o) acc[j][o] = 0.f;

    for (int c0 = 0; c0 < CIN; c0 += CI_T) {
        __syncthreads();
        for (int e = tid; e < STAGE; e += 256) {
            int ci = e / (RP * WP);
            int rem = e - ci * RP * WP;
            int r = rem / WP;
            int xx = rem - r * WP;
            int iy = row0 - 1 + r;
            int ix = xx - 1;
            float vv = 0.f;
            if (iy >= 0 && iy < H && ix >= 0 && ix < W)
                vv = in[((size_t)(b * CIN + c0 + ci) * H + iy) * W + ix];
            sx[e] = vv;
        }
        for (int e = tid; e < CI_T * 9 * 8; e += 256) {
            int rk = e >> 3;
            int o = e & 7;
            sw[e] = wT[((size_t)c0 * 9 + rk) * COUT + oc0 + o];
        }
        __syncthreads();
        #pragma unroll 1
        for (int cl = 0; cl < CI_T; ++cl) {
            const float* sxc = sx + cl * RP * WP;
            #pragma unroll
            for (int k = 0; k < 9; ++k) {
                const int ky = k / 3, kx = k % 3;
                const float4 wa = *(const float4*)(sw + (cl * 9 + k) * 8);
                const float4 wb = *(const float4*)(sw + (cl * 9 + k) * 8 + 4);
                #pragma unroll
                for (int j = 0; j < NPX; ++j) {
                    float xv = sxc[off[j] + ky * WP + kx];
                    acc[j][0] += xv * wa.x; acc[j][1] += xv * wa.y;
                    acc[j][2] += xv * wa.z; acc[j][3] += xv * wa.w;
                    acc[j][4] += xv * wb.x; acc[j][5] += xv * wb.y;
                    acc[j][6] += xv * wb.z; acc[j][7] += xv * wb.w;
                }
            }
        }
    }
    float sc[8], bi[8];
    #pragma unroll
    for (int o = 0; o < 8; ++o) {
        float s = g[oc0 + o] * rsqrtf(v[oc0 + o] + 1e-5f);
        sc[o] = s; bi[o] = (cb[oc0 + o] - m[oc0 + o]) * s + be[oc0 + o];
    }
    #pragma unroll
    for (int j = 0; j < NPX; ++j) if (val[j]) {
        int px = tid + j * 256;
        int oy = row0 + px / W, ox = px % W;
        #pragma unroll
        for (int o = 0; o < 8; ++o)
            out[((size_t)(b * COUT + oc0 + o) * H + oy) * W + ox] =
                fmaxf(acc[j][o] * sc[o] + bi[o], 0.f);
    }
}

// ---------- 2x2 maxpool stride 2 (VALID) ----------
__global__ void k_maxpool(const float* __restrict__ in, float* __restrict__ out,
                          int C, int Hin, int Win, int Hout, int Wout, int total) {
    int idx = blockIdx.x * blockDim.x + threadIdx.x;
    if (idx >= total) return;
    int ox = idx % Wout; int t = idx / Wout;
    int oy = t % Hout; t /= Hout;
    int c = t % C; int b = t / C;
    const float* p = in + ((size_t)(b * C + c) * Hin + 2 * oy) * Win + 2 * ox;
    float m0 = fmaxf(p[0], p[1]);
    float m1 = fmaxf(p[Win], p[Win + 1]);
    out[idx] = fmaxf(m0, m1);
}

// ---------- fused audio attention (both stages) + spatial GAP ----------
// EXACT R5 kernel (measured 563 us — best of the family across R5/R6/R8 variants).
__global__ void __launch_bounds__(128) k_audio_attn(
    const float* __restrict__ x,
    const float* __restrict__ wq1, const float* __restrict__ bq1,
    const float* __restrict__ wk1, const float* __restrict__ bk1,
    const float* __restrict__ wv1, const float* __restrict__ bv1,
    const float* __restrict__ wq2, const float* __restrict__ bq2,
    const float* __restrict__ wk2, const float* __restrict__ bk2,
    const float* __restrict__ wv2, const float* __restrict__ bv2,
    float* __restrict__ afeat, float* __restrict__ xgap) {
    int b = blockIdx.x, n = blockIdx.y, stage = blockIdx.z;
    const float* wq = stage ? wq2 : wq1; const float* bq = stage ? bq2 : bq1;
    const float* wk = stage ? wk2 : wk1; const float* bk = stage ? bk2 : bk1;
    const float* wv = stage ? wv2 : wv1; const float* bv = stage ? bv2 : bv1;
    __shared__ float xt[96 * 28];
    __shared__ float sb[96 * 27];
    __shared__ float pmax[4][26], psum[4][26];
    __shared__ float mx[26], sm[26];
    int tid = threadIdx.x;
    bool act = tid < 96;
    int o = act ? tid : 0;
    float bqv = act ? bq[n * 96 + tid] : 0.f;
    float bkv = act ? bk[n * 96 + tid] : 0.f;
    float bvv = act ? bv[n * 96 + tid] : 0.f;
    const float* wqb = wq + n * 9216 + o;   // [c][o] layout -> wqb[c*96]
    const float* wkb = wk + n * 9216 + o;
    const float* wvb = wv + n * 9216 + o;
    const bool do_gap = (n == 0 && stage == 0);
    float accO = 0.f, xsum = 0.f;
    const float* xb = x + (size_t)b * 96 * 234;
    for (int tile = 0; tile < 9; ++tile) {
        int p0 = tile * 26;
        __syncthreads();
        for (int e = tid; e < 2496; e += 128) {
            int c = e / 26, pp = e - c * 26;
            xt[c * 28 + pp] = xb[c * 234 + p0 + pp];
        }
        __syncthreads();
        if (do_gap && act) {
            const float* xr = xt + o * 28;
            #pragma unroll
            for (int p = 0; p < 26; ++p) xsum += xr[p];
        }
        float aq[26], ak[26], av[26];
        #pragma unroll
        for (int p = 0; p < 26; ++p) { aq[p] = bqv; ak[p] = bkv; av[p] = bvv; }
        for (int c = 0; c < 96; ++c) {
            float wqv = wqb[c * 96], wkv = wkb[c * 96], wvv2 = wvb[c * 96];
            const float* xr = xt + c * 28;
            #pragma unroll
            for (int q4 = 0; q4 < 6; ++q4) {
                float4 x4 = *(const float4*)(xr + q4 * 4);
                int p = q4 * 4;
                aq[p]   += wqv * x4.x; ak[p]   += wkv * x4.x; av[p]   += wvv2 * x4.x;
                aq[p+1] += wqv * x4.y; ak[p+1] += wkv * x4.y; av[p+1] += wvv2 * x4.y;
                aq[p+2] += wqv * x4.z; ak[p+2] += wkv * x4.z; av[p+2] += wvv2 * x4.z;
                aq[p+3] += wqv * x4.w; ak[p+3] += wkv * x4.w; av[p+3] += wvv2 * x4.w;
            }
            float2 x2 = *(const float2*)(xr + 24);
            aq[24] += wqv * x2.x; ak[24] += wkv * x2.x; av[24] += wvv2 * x2.x;
            aq[25] += wqv * x2.y; ak[25] += wkv * x2.y; av[25] += wvv2 * x2.y;
        }
        if (act) {
            #pragma unroll
            for (int p = 0; p < 26; ++p)
                sb[o * 27 + p] = aq[p] * ak[p];
        }
        __syncthreads();
        if (tid < 104) {
            int p = tid % 26, ch = tid / 26;
            int o0 = ch * 24;
            float m_ = -1e30f;
            for (int q = 0; q < 24; ++q) m_ = fmaxf(m_, sb[(o0 + q) * 27 + p]);
            pmax[ch][p] = m_;
        }
        __syncthreads();
        if (tid < 26)
            mx[tid] = fmaxf(fmaxf(pmax[0][tid], pmax[1][tid]),
                            fmaxf(pmax[2][tid], pmax[3][tid]));
        __syncthreads();
        if (tid < 104) {
            int p = tid % 26, ch = tid / 26;
            int o0 = ch * 24;
            float mv = mx[p];
            float s_ = 0.f;
            for (int q = 0; q < 24; ++q) s_ += __expf(sb[(o0 + q) * 27 + p] - mv);
            psum[ch][p] = s_;
        }
        __syncthreads();
        if (tid < 26)
            sm[tid] = psum[0][tid] + psum[1][tid] + psum[2][tid] + psum[3][tid];
        __syncthreads();
        if (act) {
            #pragma unroll
            for (int p = 0; p < 26; ++p)
                accO += __expf(sb[o * 27 + p] - mx[p]) / sm[p] * av[p];
        }
    }
    if (act) afeat[b * 1536 + n * 192 + stage * 96 + tid] = accO * (1.f / 234.f);
    if (do_gap && act) xgap[b * 96 + tid] = xsum * (1.f / 234.f);
}

// ---------- embedding lookup + input-side GRU GEMM, 8 rows/block ----------
__global__ void __launch_bounds__(320) k_gi(const int* __restrict__ tokens,
        const float* __restrict__ emb, const float* __restrict__ w_ih,
        const float* __restrict__ b_ih, float* __restrict__ GI) {
    int r0 = blockIdx.x * 8;
    int tid = threadIdx.x;
    __shared__ float er[8][200];
    for (int e = tid; e < 1600; e += 320) {
        int r = e / 200, c = e - r * 200;
        er[r][c] = emb[(size_t)tokens[r0 + r] * 200 + c];
    }
    __syncthreads();
    if (tid < 300) {
        float acc[8];
        float bv = b_ih[tid];
        #pragma unroll
        for (int r = 0; r < 8; ++r) acc[r] = bv;
        for (int k4 = 0; k4 < 50; ++k4) {
            float4 w4 = *(const float4*)(w_ih + (size_t)tid * 200 + k4 * 4);
            #pragma unroll
            for (int r = 0; r < 8; ++r) {
                float4 x4 = *(const float4*)&er[r][k4 * 4];
                acc[r] += w4.x * x4.x + w4.y * x4.y + w4.z * x4.z + w4.w * x4.w;
            }
        }
        #pragma unroll
        for (int r = 0; r < 8; ++r)
            GI[(size_t)(r0 + r) * 300 + tid] = acc[r];
    }
}

// ---------- whole GRU recurrence in ONE kernel (one block per batch row) ----------
__global__ void __launch_bounds__(320) k_gru_all(const float* __restrict__ GI,
        const float* __restrict__ w_hh, const float* __restrict__ b_hh,
        float* __restrict__ outs) {
    int b = blockIdx.x, tid = threadIdx.x;
    __shared__ float hs[100];
    __shared__ float gH[300];
    float4 wreg[25];
    float bias = 0.f;
    if (tid < 300) {
        bias = b_hh[tid];
        #pragma unroll
        for (int k4 = 0; k4 < 25; ++k4)
            wreg[k4] = *(const float4*)(w_hh + (size_t)tid * 100 + k4 * 4);
    }
    if (tid < 100) hs[tid] = 0.f;
    __syncthreads();
    for (int t = 0; t < kT; ++t) {
        if (tid < 300) {
            float gh = bias;
            #pragma unroll
            for (int k4 = 0; k4 < 25; ++k4) {
                float4 h4 = *(const float4*)&hs[k4 * 4];
                gh += wreg[k4].x * h4.x + wreg[k4].y * h4.y
                    + wreg[k4].z * h4.z + wreg[k4].w * h4.w;
            }
            gH[tid] = gh;
        }
        __syncthreads();
        if (tid < 100) {
            const float* gi = GI + ((size_t)b * kT + t) * 300;
            float r = 1.f / (1.f + expf(-(gi[tid] + gH[tid])));
            float z = 1.f / (1.f + expf(-(gi[100 + tid] + gH[100 + tid])));
            float nn = tanhf(gi[200 + tid] + r * gH[200 + tid]);
            float h2 = (1.f - z) * nn + z * hs[tid];
            hs[tid] = h2;
            outs[((size_t)b * kT + t) * 100 + tid] = h2;
        }
        __syncthreads();
    }
}

// ---------- fused text attention (both stages), t-tiled, shuffle softmax ----------
__global__ void __launch_bounds__(128) k_text_attn(const float* __restrict__ outs,
    const float* __restrict__ wq1, const float* __restrict__ bq1,
    const float* __restrict__ wk1, const float* __restrict__ bk1,
    const float* __restrict__ wv1, const float* __restrict__ bv1,
    const float* __restrict__ wq2, const float* __restrict__ bq2,
    const float* __restrict__ wk2, const float* __restrict__ bk2,
    const float* __restrict__ wv2, const float* __restrict__ bv2,
    float* __restrict__ tfeat) {
    int b = blockIdx.x, stage = blockIdx.y, n = blockIdx.z;
    const float* wq = stage ? wq2 : wq1; const float* bq = stage ? bq2 : bq1;
    const float* wk = stage ? wk2 : wk1; const float* bk = stage ? bk2 : bk1;
    const float* wv = stage ? wv2 : wv1; const float* bv = stage ? bv2 : bv1;
    int tid = threadIdx.x;
    bool act = tid < 96;
    int oo = act ? tid : 0;
    const float* wqr = wq + ((size_t)n * 96 + oo) * 100;
    const float* wkr = wk + ((size_t)n * 96 + oo) * 100;
    const float* wvr = wv + ((size_t)n * 96 + oo) * 100;
    float bqv = act ? bq[n * 96 + tid] : 0.f;
    float bkv = act ? bk[n * 96 + tid] : 0.f;
    float bvv = act ? bv[n * 96 + tid] : 0.f;
    __shared__ float rows[10][100];
    __shared__ float wredM[2][10], wredS[2][10];
    float acc = 0.f;
    int wave = tid >> 6, lane = tid & 63;
    for (int tile = 0; tile < 5; ++tile) {
        int t0 = tile * 10;
        __syncthreads();
        for (int e = tid; e < 1000; e += 128) {
            int tt = e / 100, c = e - tt * 100;
            rows[tt][c] = outs[((size_t)b * kT + t0 + tt) * 100 + c];
        }
        __syncthreads();
        float q[10], k[10], v[10];
        #pragma unroll
        for (int tt = 0; tt < 10; ++tt) { q[tt] = bqv; k[tt] = bkv; v[tt] = bvv; }
        for (int c4 = 0; c4 < 25; ++c4) {
            float4 aq = *(const float4*)(wqr + c4 * 4);
            float4 ak = *(const float4*)(wkr + c4 * 4);
            float4 av = *(const float4*)(wvr + c4 * 4);
            #pragma unroll
            for (int tt = 0; tt < 10; ++tt) {
                float4 x4 = *(const float4*)&rows[tt][c4 * 4];
                q[tt] += aq.x * x4.x + aq.y * x4.y + aq.z * x4.z + aq.w * x4.w;
                k[tt] += ak.x * x4.x + ak.y * x4.y + ak.z * x4.z + ak.w * x4.w;
                v[tt] += av.x * x4.x + av.y * x4.y + av.z * x4.z + av.w * x4.w;
            }
        }
        float s[10], e_[10];
        #pragma unroll
        for (int tt = 0; tt < 10; ++tt) s[tt] = act ? q[tt] * k[tt] : -1e30f;
        #pragma unroll
        for (int tt = 0; tt < 10; ++tt) {
            float m = s[tt];
            #pragma unroll
            for (int off = 1; off < 64; off <<= 1) m = fmaxf(m, __shfl_xor(m, off));
            if (lane == 0) wredM[wave][tt] = m;
        }
        __syncthreads();
        #pragma unroll
        for (int tt = 0; tt < 10; ++tt) {
            float mx = fmaxf(wredM[0][tt], wredM[1][tt]);
            e_[tt] = expf(s[tt] - mx);
        }
        #pragma unroll
        for (int tt = 0; tt < 10; ++tt) {
            float sm = e_[tt];
            #pragma unroll
            for (int off = 1; off < 64; off <<= 1) sm += __shfl_xor(sm, off);
            if (lane == 0) wredS[wave][tt] = sm;
        }
        __syncthreads();
        #pragma unroll
        for (int tt = 0; tt < 10; ++tt) {
            float sm = wredS[0][tt] + wredS[1][tt];
            acc += e_[tt] / sm * v[tt];
        }
    }
    if (act) tfeat[b * 1536 + stage * 768 + n * 96 + tid] = acc;
}

// ---------- cross-modal gated fusion + final logits ----------
__global__ void __launch_bounds__(128) k_final(const float* __restrict__ xgap,
    const float* __restrict__ outs, const float* __restrict__ afeat,
    const float* __restrict__ tfeat,
    const float* __restrict__ w_fa, const float* __restrict__ b_fa,
    const float* __restrict__ w_ft, const float* __restrict__ b_ft,
    const float* __restrict__ w_e, const float* __restrict__ b_e,
    float* __restrict__ out) {
    int b = blockIdx.x; int tid = threadIdx.x;
    __shared__ float xg[96], hv[100], st[100], sa[96], aat[96], atba[100];
    __shared__ float redm[2], reds[2];
    if (tid < 96) xg[tid] = xgap[b * 96 + tid];
    if (tid < 100) hv[tid] = outs[(size_t)(b * kT + kT - 1) * 100 + tid];
    __syncthreads();
    if (tid < 100) {
        float acc = b_fa[tid];
        const float* wr = w_fa + tid * 96;
        for (int c = 0; c < 96; ++c) acc += wr[c] * xg[c];
        st[tid] = acc;
    }
    if (tid < 96) {
        float acc = b_ft[tid];
        const float* wr = w_ft + tid * 100;
        for (int c = 0; c < 100; ++c) acc += wr[c] * hv[c];
        sa[tid] = acc;
    }
    __syncthreads();
    if (tid == 0) {
        float mxv = -1e30f; for (int i = 0; i < 100; ++i) mxv = fmaxf(mxv, st[i]);
        float s = 0.f; for (int i = 0; i < 100; ++i) s += expf(st[i] - mxv);
        redm[0] = mxv; reds[0] = s;
    }
    if (tid == 1) {
        float mxv = -1e30f; for (int i = 0; i < 96; ++i) mxv = fmaxf(mxv, sa[i]);
        float s = 0.f; for (int i = 0; i < 96; ++i) s += expf(sa[i] - mxv);
        redm[1] = mxv; reds[1] = s;
    }
    __syncthreads();
    if (tid < 100) atba[tid] = expf(st[tid] - redm[0]) / reds[0] * hv[tid];
    if (tid < 96)  aat[tid]  = expf(sa[tid] - redm[1]) / reds[1] * xg[tid];
    __syncthreads();
    float a0 = 0.f, a1 = 0.f, a2 = 0.f, a3 = 0.f;
    for (int col = tid; col < 3268; col += 128) {
        float f;
        if (col < 1536)      f = afeat[b * 1536 + col];
        else if (col < 3072) f = tfeat[b * 1536 + col - 1536];
        else if (col < 3168) f = aat[col - 3072];
        else                 f = atba[col - 3168];
        a0 += w_e[col] * f;            a1 += w_e[3268 + col] * f;
        a2 += w_e[2 * 3268 + col] * f; a3 += w_e[3 * 3268 + col] * f;
    }
    __shared__ float r4[4][128];
    r4[0][tid] = a0; r4[1][tid] = a1; r4[2][tid] = a2; r4[3][tid] = a3;
    __syncthreads();
    if (tid < 4) {
        float s = 0.f;
        for (int i = 0; i < 128; ++i) s += r4[tid][i];
        out[b * 4 + tid] = s + b_e[tid];
    }
}

// =====================================================================
extern "C" void kernel_launch(void* const* d_in, const int* in_sizes, int n_in,
                              void* d_out, int out_size, void* d_ws, size_t ws_size,
                              hipStream_t stream) {
    (void)in_sizes; (void)n_in; (void)out_size; (void)ws_size;
    const float* mfcc_t = (const float*)d_in[0];
    const float* mfcc_f = (const float*)d_in[1];
    const float* mfcc_c = (const float*)d_in[2];
    const int*   tokens = (const int*)d_in[3];
    const float *w1a = (const float*)d_in[5],  *b1a = (const float*)d_in[6],
                *g1a = (const float*)d_in[7],  *be1a = (const float*)d_in[8],
                *m1a = (const float*)d_in[9],  *v1a = (const float*)d_in[10];
    const float *w1b = (const float*)d_in[11], *b1b = (const float*)d_in[12],
                *g1b = (const float*)d_in[13], *be1b = (const float*)d_in[14],
                *m1b = (const float*)d_in[15], *v1b = (const float*)d_in[16];
    const float *w2 = (const float*)d_in[17], *b2 = (const float*)d_in[18],
                *g2 = (const float*)d_in[19], *be2 = (const float*)d_in[20],
                *m2 = (const float*)d_in[21], *v2 = (const float*)d_in[22];
    const float *w3 = (const float*)d_in[23], *b3 = (const float*)d_in[24],
                *g3 = (const float*)d_in[25], *be3 = (const float*)d_in[26],
                *m3 = (const float*)d_in[27], *v3 = (const float*)d_in[28];
    const float *w4 = (const float*)d_in[29], *b4 = (const float*)d_in[30],
                *g4 = (const float*)d_in[31], *be4 = (const float*)d_in[32],
                *m4 = (const float*)d_in[33], *v4 = (const float*)d_in[34];
    const float *wq_a1 = (const float*)d_in[35], *bq_a1 = (const float*)d_in[36],
                *wk_a1 = (const float*)d_in[37], *bk_a1 = (const float*)d_in[38],
                *wv_a1 = (const float*)d_in[39], *bv_a1 = (const float*)d_in[40];
    const float *wq_a2 = (const float*)d_in[41], *bq_a2 = (const float*)d_in[42],
                *wk_a2 = (const float*)d_in[43], *bk_a2 = (const float*)d_in[44],
                *wv_a2 = (const float*)d_in[45], *bv_a2 = (const float*)d_in[46];
    const float *emb  = (const float*)d_in[47];
    const float *w_ih = (const float*)d_in[48], *w_hh = (const float*)d_in[49],
                *b_ih = (const float*)d_in[50], *b_hh = (const float*)d_in[51];
    const float *wq_t1 = (const float*)d_in[52], *bq_t1 = (const float*)d_in[53],
                *wk_t1 = (const float*)d_in[54], *bk_t1 = (const float*)d_in[55],
                *wv_t1 = (const float*)d_in[56], *bv_t1 = (const float*)d_in[57];
    const float *wq_t2 = (const float*)d_in[58], *bq_t2 = (const float*)d_in[59],
                *wk_t2 = (const float*)d_in[60], *bk_t2 = (const float*)d_in[61],
                *wv_t2 = (const float*)d_in[62], *bv_t2 = (const float*)d_in[63];
    const float *w_fa = (const float*)d_in[64], *b_fa = (const float*)d_in[65],
                *w_ft = (const float*)d_in[66], *b_ft = (const float*)d_in[67],
                *w_e  = (const float*)d_in[68], *b_e  = (const float*)d_in[69];

    float* ws = (float*)d_ws;
    const size_t Z0 = 0;                 // c2 -> c3 -> x4
    const size_t Z1 = 22091776ull;       // x1 -> p2 -> p3 -> GI
    const size_t OUTS  = 34072576ull;    // conv-wT (early) then GRU outputs
    const size_t AFEAT = 34712576ull;
    const size_t TFEAT = 34909184ull;
    const size_t XGAP  = 35105792ull;
    const size_t WT    = 35118080ull;
    float* X1 = ws + Z1;
    float* C2 = ws + Z0;  float* P2 = ws + Z1;
    float* C3 = ws + Z0;  float* P3 = ws + Z1;
    float* X4 = ws + Z0;  float* GI = ws + Z1;
    float* outs  = ws + OUTS;
    float* afeat = ws + AFEAT;
    float* tfeat = ws + TFEAT;
    float* xgap  = ws + XGAP;
    float* wqa1t = ws + WT;
    float* wka1t = wqa1t + 73728; float* wva1t = wka1t + 73728;
    float* wqa2t = wva1t + 73728; float* wka2t = wqa2t + 73728; float* wva2t = wka2t + 73728;
    // conv weight transposes parked in the (still dead) GRU outs region
    float* wT2 = outs;            //  6,912
    float* wT3 = outs + 6912;     // 18,432
    float* wT4 = outs + 25344;    // 55,296

    // ----- all weight transposes in ONE launch -----
    TPack tp;
    tp.d[0] = {wq_a1, wqa1t, 96, 96, 73728};
    tp.d[1] = {wk_a1, wka1t, 96, 96, 73728};
    tp.d[2] = {wv_a1, wva1t, 96, 96, 73728};
    tp.d[3] = {wq_a2, wqa2t, 96, 96, 73728};
    tp.d[4] = {wk_a2, wka2t, 96, 96, 73728};
    tp.d[5] = {wv_a2, wva2t, 96, 96, 73728};
    tp.d[6] = {w2, wT2, 32, 216, 6912};
    tp.d[7] = {w3, wT3, 64, 288, 18432};
    tp.d[8] = {w4, wT4, 96, 576, 55296};
    k_transpose_pack<<<dim3(288, 9), 256, 0, stream>>>(tp);

    // ----- fused stem (register-window conv taps) -----
    k_stem<<<46800, 256, 0, stream>>>(mfcc_t, mfcc_f, mfcc_c,
        w1a, b1a, g1a, be1a, m1a, v1a,
        w1b, b1b, g1b, be1b, m1b, v1b, X1, 11980800);
    k_conv3x3_tiled<24, 8, 25, 156, 9, 6><<<dim3(128, 3, 4), 256, 0, stream>>>(
        X1, wT2, b2, g2, be2, m2, v2, C2, 32);
    k_maxpool<<<14976, 256, 0, stream>>>(C2, P2, 32, 25, 156, 12, 78, 3833856);
    k_conv3x3_tiled<32, 8, 12, 78, 12, 4><<<dim3(128, 1, 8), 256, 0, stream>>>(
        P2, wT3, b3, g3, be3, m3, v3, C3, 64);
    k_maxpool<<<7488, 256, 0, stream>>>(C3, P3, 64, 12, 78, 6, 39, 1916928);
    k_conv3x3_tiled<64, 16, 6, 39, 6, 1><<<dim3(128, 1, 12), 256, 0, stream>>>(
        P3, wT4, b4, g4, be4, m4, v4, X4, 96);

    // ----- audio attention (+GAP folded in): exact R5 best -----
    k_audio_attn<<<dim3(kB, 8, 2), 128, 0, stream>>>(X4,
        wqa1t, bq_a1, wka1t, bk_a1, wva1t, bv_a1,
        wqa2t, bq_a2, wka2t, bk_a2, wva2t, bv_a2, afeat, xgap);

    // ----- text branch -----
    k_gi<<<kB * kT / 8, 320, 0, stream>>>(tokens, emb, w_ih, b_ih, GI);
    k_gru_all<<<kB, 320, 0, stream>>>(GI, w_hh, b_hh, outs);
    k_text_attn<<<dim3(kB, 2, 8), 128, 0, stream>>>(outs,
        wq_t1, bq_t1, wk_t1, bk_t1, wv_t1, bv_t1,
        wq_t2, bq_t2, wk_t2, bk_t2, wv_t2, bv_t2, tfeat);

    // ----- fusion + logits -----
    k_final<<<kB, 128, 0, stream>>>(xgap, outs, afeat, tfeat,
                                    w_fa, b_fa, w_ft, b_ft, w_e, b_e, (float*)d_out);
}

// Round 11
// 1571.054 us; speedup vs baseline: 1.1901x; 1.0628x over previous
//
#include <hip/hip_runtime.h>
#include <math.h>

// ---------------- constants ----------------
static constexpr int kB = 128;
static constexpr int kT = 50;

// ---------- packed transpose [N][O][C] -> [N][C][O], 15 segments, one launch ----------
struct TDesc { const float* src; float* dst; int O; int C; int total; };
struct TPack { TDesc d[15]; };
__global__ void k_transpose_pack(TPack p) {
    TDesc t = p.d[blockIdx.y];
    int idx = blockIdx.x * 256 + threadIdx.x;
    if (idx >= t.total) return;
    int o = idx % t.O; int r = idx / t.O; int c = r % t.C; int n = r / t.C;
    t.dst[idx] = t.src[((size_t)n * t.O + o) * t.C + c];
}

// ---------- fused stem: conv1{a,b,b} + BN + ReLU + bilinear resize + concat ----------
// Register-window version (R9-measured good): union window 18/21 loads vs 40/48.
__global__ void k_stem(const float* __restrict__ mt, const float* __restrict__ mf,
                       const float* __restrict__ mc,
                       const float* __restrict__ w1a, const float* __restrict__ b1a,
                       const float* __restrict__ g1a, const float* __restrict__ be1a,
                       const float* __restrict__ m1a, const float* __restrict__ v1a,
                       const float* __restrict__ w1b, const float* __restrict__ b1b,
                       const float* __restrict__ g1b, const float* __restrict__ be1b,
                       const float* __restrict__ m1b, const float* __restrict__ v1b,
                       float* __restrict__ out, int total) {
    int idx = blockIdx.x * blockDim.x + threadIdx.x;
    if (idx >= total) return;
    int ox = idx % 156; int t = idx / 156;
    int oy = t % 25; t /= 25;
    int ch = t % 24; int b = t / 24;
    int grp = ch >> 3, c = ch & 7;
    const float* src; int Hc, Wc;
    const float *wb, *cb, *g, *be, *m, *v;
    if (grp == 0) { src = mt; Hc = 196; Wc = 39; wb = w1a + c * 10;
                    cb = b1a; g = g1a; be = be1a; m = m1a; v = v1a; }
    else          { src = (grp == 1 ? mf : mc); Hc = 199; Wc = 35; wb = w1b + c * 12;
                    cb = b1b; g = g1b; be = be1b; m = m1b; v = v1b; }
    float s = g[c] * rsqrtf(v[c] + 1e-5f);
    float bias = (cb[c] - m[c]) * s + be[c];
    float sy = (oy + 0.5f) * ((float)Hc / 25.f) - 0.5f;
    float sx = (ox + 0.5f) * ((float)Wc / 156.f) - 0.5f;
    float fy0 = floorf(sy), fx0 = floorf(sx);
    float fy = sy - fy0, fx = sx - fx0;
    int y0 = (int)fy0, x0 = (int)fx0;
    int y0c = min(max(y0, 0), Hc - 1), y1c = min(max(y0 + 1, 0), Hc - 1);
    int x0c = min(max(x0, 0), Wc - 1), x1c = min(max(x0 + 1, 0), Wc - 1);
    bool xs = (x1c == x0c), ys = (y1c == y0c);
    const float* p = src + (size_t)b * 8000;   // input 200 x 40
    float t00, t01, t10, t11;
    if (grp == 0) {
        float W[6][3];
        #pragma unroll
        for (int r = 0; r < 6; ++r) {
            int rr = min(y0c + r, 199);
            #pragma unroll
            for (int cc = 0; cc < 3; ++cc)
                W[r][cc] = p[rr * 40 + min(x0c + cc, 39)];
        }
        float a00 = 0.f, a01 = 0.f, a10 = 0.f, a11 = 0.f;
        #pragma unroll
        for (int ky = 0; ky < 5; ++ky)
            #pragma unroll
            for (int kx = 0; kx < 2; ++kx) {
                float wv = wb[ky * 2 + kx];
                a00 += W[ky][kx] * wv;     a01 += W[ky][kx + 1] * wv;
                a10 += W[ky + 1][kx] * wv; a11 += W[ky + 1][kx + 1] * wv;
            }
        t00 = a00;
        t01 = xs ? a00 : a01;
        t10 = ys ? a00 : a10;
        t11 = xs ? (ys ? a00 : a10) : (ys ? a01 : a11);
    } else {
        float W[3][7];
        #pragma unroll
        for (int r = 0; r < 3; ++r) {
            int rr = min(y0c + r, 199);
            #pragma unroll
            for (int cc = 0; cc < 7; ++cc)
                W[r][cc] = p[rr * 40 + min(x0c + cc, 39)];
        }
        float a00 = 0.f, a01 = 0.f, a10 = 0.f, a11 = 0.f;
        #pragma unroll
        for (int ky = 0; ky < 2; ++ky)
            #pragma unroll
            for (int kx = 0; kx < 6; ++kx) {
                float wv = wb[ky * 6 + kx];
                a00 += W[ky][kx] * wv;     a01 += W[ky][kx + 1] * wv;
                a10 += W[ky + 1][kx] * wv; a11 += W[ky + 1][kx + 1] * wv;
            }
        t00 = a00;
        t01 = xs ? a00 : a01;
        t10 = ys ? a00 : a10;
        t11 = xs ? (ys ? a00 : a10) : (ys ? a01 : a11);
    }
    float r00 = fmaxf(t00 * s + bias, 0.f), r01 = fmaxf(t01 * s + bias, 0.f);
    float r10 = fmaxf(t10 * s + bias, 0.f), r11 = fmaxf(t11 * s + bias, 0.f);
    out[idx] = r00 * (1.f - fy) * (1.f - fx) + r01 * (1.f - fy) * fx
             + r10 * fy * (1.f - fx) + r11 * fy * fx;
}

// ---------- LDS-tiled 3x3 conv, pad 1, fused BN(eval) + ReLU ----------
template<int CIN, int CI_T, int H, int W, int ROWS, int NPX>
__global__ void __launch_bounds__(256) k_conv3x3_tiled(
    const float* __restrict__ in, const float* __restrict__ wT,
    const float* __restrict__ cb, const float* __restrict__ g,
    const float* __restrict__ be, const float* __restrict__ m,
    const float* __restrict__ v, float* __restrict__ out, int COUT) {
    constexpr int WP = W + 2;
    constexpr int RP = ROWS + 2;
    constexpr int STAGE = CI_T * RP * WP;
    __shared__ float sx[STAGE];
    __shared__ float sw[CI_T * 9 * 8];
    const int b = blockIdx.x, rt = blockIdx.y, oc0 = blockIdx.z * 8;
    const int row0 = rt * ROWS;
    const int tid = threadIdx.x;

    int off[NPX]; bool val[NPX];
    #pragma unroll
    for (int j = 0; j < NPX; ++j) {
        int px = tid + j * 256;
        int oy = px / W, ox = px - oy * W;
        bool ok = (px < ROWS * W) && (row0 + oy < H);
        val[j] = ok;
        off[j] = ok ? (oy * WP + ox) : 0;
    }

    float acc[NPX][8];
    #pragma unroll
    for (int j = 0; j < NPX; ++j)
        #pragma unroll
        for (int o = 0; o < 8; ++o) acc[j][o] = 0.f;

    for (int c0 = 0; c0 < CIN; c0 += CI_T) {
        __syncthreads();
        for (int e = tid; e < STAGE; e += 256) {
            int ci = e / (RP * WP);
            int rem = e - ci * RP * WP;
            int r = rem / WP;
            int xx = rem - r * WP;
            int iy = row0 - 1 + r;
            int ix = xx - 1;
            float vv = 0.f;
            if (iy >= 0 && iy < H && ix >= 0 && ix < W)
                vv = in[((size_t)(b * CIN + c0 + ci) * H + iy) * W + ix];
            sx[e] = vv;
        }
        for (int e = tid; e < CI_T * 9 * 8; e += 256) {
            int rk = e >> 3;
            int o = e & 7;
            sw[e] = wT[((size_t)c0 * 9 + rk) * COUT + oc0 + o];
        }
        __syncthreads();
        #pragma unroll 1
        for (int cl = 0; cl < CI_T; ++cl) {
            const float* sxc = sx + cl * RP * WP;
            #pragma unroll
            for (int k = 0; k < 9; ++k) {
                const int ky = k / 3, kx = k % 3;
                const float4 wa = *(const float4*)(sw + (cl * 9 + k) * 8);
                const float4 wb = *(const float4*)(sw + (cl * 9 + k) * 8 + 4);
                #pragma unroll
                for (int j = 0; j < NPX; ++j) {
                    float xv = sxc[off[j] + ky * WP + kx];
                    acc[j][0] += xv * wa.x; acc[j][1] += xv * wa.y;
                    acc[j][2] += xv * wa.z; acc[j][3] += xv * wa.w;
                    acc[j][4] += xv * wb.x; acc[j][5] += xv * wb.y;
                    acc[j][6] += xv * wb.z; acc[j][7] += xv * wb.w;
                }
            }
        }
    }
    float sc[8], bi[8];
    #pragma unroll
    for (int o = 0; o < 8; ++o) {
        float s = g[oc0 + o] * rsqrtf(v[oc0 + o] + 1e-5f);
        sc[o] = s; bi[o] = (cb[oc0 + o] - m[oc0 + o]) * s + be[oc0 + o];
    }
    #pragma unroll
    for (int j = 0; j < NPX; ++j) if (val[j]) {
        int px = tid + j * 256;
        int oy = row0 + px / W, ox = px % W;
        #pragma unroll
        for (int o = 0; o < 8; ++o)
            out[((size_t)(b * COUT + oc0 + o) * H + oy) * W + ox] =
                fmaxf(acc[j][o] * sc[o] + bi[o], 0.f);
    }
}

// ---------- 2x2 maxpool stride 2 (VALID) ----------
__global__ void k_maxpool(const float* __restrict__ in, float* __restrict__ out,
                          int C, int Hin, int Win, int Hout, int Wout, int total) {
    int idx = blockIdx.x * blockDim.x + threadIdx.x;
    if (idx >= total) return;
    int ox = idx % Wout; int t = idx / Wout;
    int oy = t % Hout; t /= Hout;
    int c = t % C; int b = t / C;
    const float* p = in + ((size_t)(b * C + c) * Hin + 2 * oy) * Win + 2 * ox;
    float m0 = fmaxf(p[0], p[1]);
    float m1 = fmaxf(p[Win], p[Win + 1]);
    out[idx] = fmaxf(m0, m1);
}

// ---------- fused audio attention (both stages) + spatial GAP ----------
// EXACT R5 kernel (measured 563-575 us — best across R5/R6/R8 variants).
__global__ void __launch_bounds__(128) k_audio_attn(
    const float* __restrict__ x,
    const float* __restrict__ wq1, const float* __restrict__ bq1,
    const float* __restrict__ wk1, const float* __restrict__ bk1,
    const float* __restrict__ wv1, const float* __restrict__ bv1,
    const float* __restrict__ wq2, const float* __restrict__ bq2,
    const float* __restrict__ wk2, const float* __restrict__ bk2,
    const float* __restrict__ wv2, const float* __restrict__ bv2,
    float* __restrict__ afeat, float* __restrict__ xgap) {
    int b = blockIdx.x, n = blockIdx.y, stage = blockIdx.z;
    const float* wq = stage ? wq2 : wq1; const float* bq = stage ? bq2 : bq1;
    const float* wk = stage ? wk2 : wk1; const float* bk = stage ? bk2 : bk1;
    const float* wv = stage ? wv2 : wv1; const float* bv = stage ? bv2 : bv1;
    __shared__ float xt[96 * 28];
    __shared__ float sb[96 * 27];
    __shared__ float pmax[4][26], psum[4][26];
    __shared__ float mx[26], sm[26];
    int tid = threadIdx.x;
    bool act = tid < 96;
    int o = act ? tid : 0;
    float bqv = act ? bq[n * 96 + tid] : 0.f;
    float bkv = act ? bk[n * 96 + tid] : 0.f;
    float bvv = act ? bv[n * 96 + tid] : 0.f;
    const float* wqb = wq + n * 9216 + o;   // [c][o] layout -> wqb[c*96]
    const float* wkb = wk + n * 9216 + o;
    const float* wvb = wv + n * 9216 + o;
    const bool do_gap = (n == 0 && stage == 0);
    float accO = 0.f, xsum = 0.f;
    const float* xb = x + (size_t)b * 96 * 234;
    for (int tile = 0; tile < 9; ++tile) {
        int p0 = tile * 26;
        __syncthreads();
        for (int e = tid; e < 2496; e += 128) {
            int c = e / 26, pp = e - c * 26;
            xt[c * 28 + pp] = xb[c * 234 + p0 + pp];
        }
        __syncthreads();
        if (do_gap && act) {
            const float* xr = xt + o * 28;
            #pragma unroll
            for (int p = 0; p < 26; ++p) xsum += xr[p];
        }
        float aq[26], ak[26], av[26];
        #pragma unroll
        for (int p = 0; p < 26; ++p) { aq[p] = bqv; ak[p] = bkv; av[p] = bvv; }
        for (int c = 0; c < 96; ++c) {
            float wqv = wqb[c * 96], wkv = wkb[c * 96], wvv2 = wvb[c * 96];
            const float* xr = xt + c * 28;
            #pragma unroll
            for (int q4 = 0; q4 < 6; ++q4) {
                float4 x4 = *(const float4*)(xr + q4 * 4);
                int p = q4 * 4;
                aq[p]   += wqv * x4.x; ak[p]   += wkv * x4.x; av[p]   += wvv2 * x4.x;
                aq[p+1] += wqv * x4.y; ak[p+1] += wkv * x4.y; av[p+1] += wvv2 * x4.y;
                aq[p+2] += wqv * x4.z; ak[p+2] += wkv * x4.z; av[p+2] += wvv2 * x4.z;
                aq[p+3] += wqv * x4.w; ak[p+3] += wkv * x4.w; av[p+3] += wvv2 * x4.w;
            }
            float2 x2 = *(const float2*)(xr + 24);
            aq[24] += wqv * x2.x; ak[24] += wkv * x2.x; av[24] += wvv2 * x2.x;
            aq[25] += wqv * x2.y; ak[25] += wkv * x2.y; av[25] += wvv2 * x2.y;
        }
        if (act) {
            #pragma unroll
            for (int p = 0; p < 26; ++p)
                sb[o * 27 + p] = aq[p] * ak[p];
        }
        __syncthreads();
        if (tid < 104) {
            int p = tid % 26, ch = tid / 26;
            int o0 = ch * 24;
            float m_ = -1e30f;
            for (int q = 0; q < 24; ++q) m_ = fmaxf(m_, sb[(o0 + q) * 27 + p]);
            pmax[ch][p] = m_;
        }
        __syncthreads();
        if (tid < 26)
            mx[tid] = fmaxf(fmaxf(pmax[0][tid], pmax[1][tid]),
                            fmaxf(pmax[2][tid], pmax[3][tid]));
        __syncthreads();
        if (tid < 104) {
            int p = tid % 26, ch = tid / 26;
            int o0 = ch * 24;
            float mv = mx[p];
            float s_ = 0.f;
            for (int q = 0; q < 24; ++q) s_ += __expf(sb[(o0 + q) * 27 + p] - mv);
            psum[ch][p] = s_;
        }
        __syncthreads();
        if (tid < 26)
            sm[tid] = psum[0][tid] + psum[1][tid] + psum[2][tid] + psum[3][tid];
        __syncthreads();
        if (act) {
            #pragma unroll
            for (int p = 0; p < 26; ++p)
                accO += __expf(sb[o * 27 + p] - mx[p]) / sm[p] * av[p];
        }
    }
    if (act) afeat[b * 1536 + n * 192 + stage * 96 + tid] = accO * (1.f / 234.f);
    if (do_gap && act) xgap[b * 96 + tid] = xsum * (1.f / 234.f);
}

// ---------- embedding lookup + input-side GRU GEMM, 8 rows/block ----------
__global__ void __launch_bounds__(320) k_gi(const int* __restrict__ tokens,
        const float* __restrict__ emb, const float* __restrict__ w_ih,
        const float* __restrict__ b_ih, float* __restrict__ GI) {
    int r0 = blockIdx.x * 8;
    int tid = threadIdx.x;
    __shared__ float er[8][200];
    for (int e = tid; e < 1600; e += 320) {
        int r = e / 200, c = e - r * 200;
        er[r][c] = emb[(size_t)tokens[r0 + r] * 200 + c];
    }
    __syncthreads();
    if (tid < 300) {
        float acc[8];
        float bv = b_ih[tid];
        #pragma unroll
        for (int r = 0; r < 8; ++r) acc[r] = bv;
        for (int k4 = 0; k4 < 50; ++k4) {
            float4 w4 = *(const float4*)(w_ih + (size_t)tid * 200 + k4 * 4);
            #pragma unroll
            for (int r = 0; r < 8; ++r) {
                float4 x4 = *(const float4*)&er[r][k4 * 4];
                acc[r] += w4.x * x4.x + w4.y * x4.y + w4.z * x4.z + w4.w * x4.w;
            }
        }
        #pragma unroll
        for (int r = 0; r < 8; ++r)
            GI[(size_t)(r0 + r) * 300 + tid] = acc[r];
    }
}

// ---------- whole GRU recurrence in ONE kernel (one block per batch row) ----------
__global__ void __launch_bounds__(320) k_gru_all(const float* __restrict__ GI,
        const float* __restrict__ w_hh, const float* __restrict__ b_hh,
        float* __restrict__ outs) {
    int b = blockIdx.x, tid = threadIdx.x;
    __shared__ float hs[100];
    __shared__ float gH[300];
    float4 wreg[25];
    float bias = 0.f;
    if (tid < 300) {
        bias = b_hh[tid];
        #pragma unroll
        for (int k4 = 0; k4 < 25; ++k4)
            wreg[k4] = *(const float4*)(w_hh + (size_t)tid * 100 + k4 * 4);
    }
    if (tid < 100) hs[tid] = 0.f;
    __syncthreads();
    for (int t = 0; t < kT; ++t) {
        if (tid < 300) {
            float gh = bias;
            #pragma unroll
            for (int k4 = 0; k4 < 25; ++k4) {
                float4 h4 = *(const float4*)&hs[k4 * 4];
                gh += wreg[k4].x * h4.x + wreg[k4].y * h4.y
                    + wreg[k4].z * h4.z + wreg[k4].w * h4.w;
            }
            gH[tid] = gh;
        }
        __syncthreads();
        if (tid < 100) {
            const float* gi = GI + ((size_t)b * kT + t) * 300;
            float r = 1.f / (1.f + expf(-(gi[tid] + gH[tid])));
            float z = 1.f / (1.f + expf(-(gi[100 + tid] + gH[100 + tid])));
            float nn = tanhf(gi[200 + tid] + r * gH[200 + tid]);
            float h2 = (1.f - z) * nn + z * hs[tid];
            hs[tid] = h2;
            outs[((size_t)b * kT + t) * 100 + tid] = h2;
        }
        __syncthreads();
    }
}

// ---------- fused text attention (both stages), t-tiled, shuffle softmax ----------
// Weights TRANSPOSED to [n][c][o] (lane=o coalesced, matching the audio kernel)
// replacing the per-lane stride-400B gather of the raw [n][o][c] layout.
__global__ void __launch_bounds__(128) k_text_attn(const float* __restrict__ outs,
    const float* __restrict__ wq1, const float* __restrict__ bq1,
    const float* __restrict__ wk1, const float* __restrict__ bk1,
    const float* __restrict__ wv1, const float* __restrict__ bv1,
    const float* __restrict__ wq2, const float* __restrict__ bq2,
    const float* __restrict__ wk2, const float* __restrict__ bk2,
    const float* __restrict__ wv2, const float* __restrict__ bv2,
    float* __restrict__ tfeat) {
    int b = blockIdx.x, stage = blockIdx.y, n = blockIdx.z;
    const float* wq = stage ? wq2 : wq1; const float* bq = stage ? bq2 : bq1;
    const float* wk = stage ? wk2 : wk1; const float* bk = stage ? bk2 : bk1;
    const float* wv = stage ? wv2 : wv1; const float* bv = stage ? bv2 : bv1;
    int tid = threadIdx.x;
    bool act = tid < 96;
    int oo = act ? tid : 0;
    // transposed layout: w[n*9600 + c*96 + o]
    const float* wqc = wq + n * 9600 + oo;
    const float* wkc = wk + n * 9600 + oo;
    const float* wvc = wv + n * 9600 + oo;
    float bqv = act ? bq[n * 96 + tid] : 0.f;
    float bkv = act ? bk[n * 96 + tid] : 0.f;
    float bvv = act ? bv[n * 96 + tid] : 0.f;
    __shared__ float rows[10][100];
    __shared__ float wredM[2][10], wredS[2][10];
    float acc = 0.f;
    int wave = tid >> 6, lane = tid & 63;
    for (int tile = 0; tile < 5; ++tile) {
        int t0 = tile * 10;
        __syncthreads();
        for (int e = tid; e < 1000; e += 128) {
            int tt = e / 100, c = e - tt * 100;
            rows[tt][c] = outs[((size_t)b * kT + t0 + tt) * 100 + c];
        }
        __syncthreads();
        float q[10], k[10], v[10];
        #pragma unroll
        for (int tt = 0; tt < 10; ++tt) { q[tt] = bqv; k[tt] = bkv; v[tt] = bvv; }
        for (int c4 = 0; c4 < 25; ++c4) {
            int cb = c4 * 4 * 96;
            float q0 = wqc[cb], q1 = wqc[cb + 96], q2 = wqc[cb + 192], q3 = wqc[cb + 288];
            float k0 = wkc[cb], k1 = wkc[cb + 96], k2 = wkc[cb + 192], k3 = wkc[cb + 288];
            float v0 = wvc[cb], v1 = wvc[cb + 96], v2 = wvc[cb + 192], v3 = wvc[cb + 288];
            #pragma unroll
            for (int tt = 0; tt < 10; ++tt) {
                float4 x4 = *(const float4*)&rows[tt][c4 * 4];
                q[tt] += q0 * x4.x + q1 * x4.y + q2 * x4.z + q3 * x4.w;
                k[tt] += k0 * x4.x + k1 * x4.y + k2 * x4.z + k3 * x4.w;
                v[tt] += v0 * x4.x + v1 * x4.y + v2 * x4.z + v3 * x4.w;
            }
        }
        float s[10], e_[10];
        #pragma unroll
        for (int tt = 0; tt < 10; ++tt) s[tt] = act ? q[tt] * k[tt] : -1e30f;
        #pragma unroll
        for (int tt = 0; tt < 10; ++tt) {
            float m = s[tt];
            #pragma unroll
            for (int off = 1; off < 64; off <<= 1) m = fmaxf(m, __shfl_xor(m, off));
            if (lane == 0) wredM[wave][tt] = m;
        }
        __syncthreads();
        #pragma unroll
        for (int tt = 0; tt < 10; ++tt) {
            float mx = fmaxf(wredM[0][tt], wredM[1][tt]);
            e_[tt] = expf(s[tt] - mx);
        }
        #pragma unroll
        for (int tt = 0; tt < 10; ++tt) {
            float sm = e_[tt];
            #pragma unroll
            for (int off = 1; off < 64; off <<= 1) sm += __shfl_xor(sm, off);
            if (lane == 0) wredS[wave][tt] = sm;
        }
        __syncthreads();
        #pragma unroll
        for (int tt = 0; tt < 10; ++tt) {
            float sm = wredS[0][tt] + wredS[1][tt];
            acc += e_[tt] / sm * v[tt];
        }
    }
    if (act) tfeat[b * 1536 + stage * 768 + n * 96 + tid] = acc;
}

// ---------- cross-modal gated fusion + final logits ----------
__global__ void __launch_bounds__(128) k_final(const float* __restrict__ xgap,
    const float* __restrict__ outs, const float* __restrict__ afeat,
    const float* __restrict__ tfeat,
    const float* __restrict__ w_fa, const float* __restrict__ b_fa,
    const float* __restrict__ w_ft, const float* __restrict__ b_ft,
    const float* __restrict__ w_e, const float* __restrict__ b_e,
    float* __restrict__ out) {
    int b = blockIdx.x; int tid = threadIdx.x;
    __shared__ float xg[96], hv[100], st[100], sa[96], aat[96], atba[100];
    __shared__ float redm[2], reds[2];
    if (tid < 96) xg[tid] = xgap[b * 96 + tid];
    if (tid < 100) hv[tid] = outs[(size_t)(b * kT + kT - 1) * 100 + tid];
    __syncthreads();
    if (tid < 100) {
        float acc = b_fa[tid];
        const float* wr = w_fa + tid * 96;
        for (int c = 0; c < 96; ++c) acc += wr[c] * xg[c];
        st[tid] = acc;
    }
    if (tid < 96) {
        float acc = b_ft[tid];
        const float* wr = w_ft + tid * 100;
        for (int c = 0; c < 100; ++c) acc += wr[c] * hv[c];
        sa[tid] = acc;
    }
    __syncthreads();
    if (tid == 0) {
        float mxv = -1e30f; for (int i = 0; i < 100; ++i) mxv = fmaxf(mxv, st[i]);
        float s = 0.f; for (int i = 0; i < 100; ++i) s += expf(st[i] - mxv);
        redm[0] = mxv; reds[0] = s;
    }
    if (tid == 1) {
        float mxv = -1e30f; for (int i = 0; i < 96; ++i) mxv = fmaxf(mxv, sa[i]);
        float s = 0.f; for (int i = 0; i < 96; ++i) s += expf(sa[i] - mxv);
        redm[1] = mxv; reds[1] = s;
    }
    __syncthreads();
    if (tid < 100) atba[tid] = expf(st[tid] - redm[0]) / reds[0] * hv[tid];
    if (tid < 96)  aat[tid]  = expf(sa[tid] - redm[1]) / reds[1] * xg[tid];
    __syncthreads();
    float a0 = 0.f, a1 = 0.f, a2 = 0.f, a3 = 0.f;
    for (int col = tid; col < 3268; col += 128) {
        float f;
        if (col < 1536)      f = afeat[b * 1536 + col];
        else if (col < 3072) f = tfeat[b * 1536 + col - 1536];
        else if (col < 3168) f = aat[col - 3072];
        else                 f = atba[col - 3168];
        a0 += w_e[col] * f;            a1 += w_e[3268 + col] * f;
        a2 += w_e[2 * 3268 + col] * f; a3 += w_e[3 * 3268 + col] * f;
    }
    __shared__ float r4[4][128];
    r4[0][tid] = a0; r4[1][tid] = a1; r4[2][tid] = a2; r4[3][tid] = a3;
    __syncthreads();
    if (tid < 4) {
        float s = 0.f;
        for (int i = 0; i < 128; ++i) s += r4[tid][i];
        out[b * 4 + tid] = s + b_e[tid];
    }
}

// =====================================================================
extern "C" void kernel_launch(void* const* d_in, const int* in_sizes, int n_in,
                              void* d_out, int out_size, void* d_ws, size_t ws_size,
                              hipStream_t stream) {
    (void)in_sizes; (void)n_in; (void)out_size; (void)ws_size;
    const float* mfcc_t = (const float*)d_in[0];
    const float* mfcc_f = (const float*)d_in[1];
    const float* mfcc_c = (const float*)d_in[2];
    const int*   tokens = (const int*)d_in[3];
    const float *w1a = (const float*)d_in[5],  *b1a = (const float*)d_in[6],
                *g1a = (const float*)d_in[7],  *be1a = (const float*)d_in[8],
                *m1a = (const float*)d_in[9],  *v1a = (const float*)d_in[10];
    const float *w1b = (const float*)d_in[11], *b1b = (const float*)d_in[12],
                *g1b = (const float*)d_in[13], *be1b = (const float*)d_in[14],
                *m1b = (const float*)d_in[15], *v1b = (const float*)d_in[16];
    const float *w2 = (const float*)d_in[17], *b2 = (const float*)d_in[18],
                *g2 = (const float*)d_in[19], *be2 = (const float*)d_in[20],
                *m2 = (const float*)d_in[21], *v2 = (const float*)d_in[22];
    const float *w3 = (const float*)d_in[23], *b3 = (const float*)d_in[24],
                *g3 = (const float*)d_in[25], *be3 = (const float*)d_in[26],
                *m3 = (const float*)d_in[27], *v3 = (const float*)d_in[28];
    const float *w4 = (const float*)d_in[29], *b4 = (const float*)d_in[30],
                *g4 = (const float*)d_in[31], *be4 = (const float*)d_in[32],
                *m4 = (const float*)d_in[33], *v4 = (const float*)d_in[34];
    const float *wq_a1 = (const float*)d_in[35], *bq_a1 = (const float*)d_in[36],
                *wk_a1 = (const float*)d_in[37], *bk_a1 = (const float*)d_in[38],
                *wv_a1 = (const float*)d_in[39], *bv_a1 = (const float*)d_in[40];
    const float *wq_a2 = (const float*)d_in[41], *bq_a2 = (const float*)d_in[42],
                *wk_a2 = (const float*)d_in[43], *bk_a2 = (const float*)d_in[44],
                *wv_a2 = (const float*)d_in[45], *bv_a2 = (const float*)d_in[46];
    const float *emb  = (const float*)d_in[47];
    const float *w_ih = (const float*)d_in[48], *w_hh = (const float*)d_in[49],
                *b_ih = (const float*)d_in[50], *b_hh = (const float*)d_in[51];
    const float *wq_t1 = (const float*)d_in[52], *bq_t1 = (const float*)d_in[53],
                *wk_t1 = (const float*)d_in[54], *bk_t1 = (const float*)d_in[55],
                *wv_t1 = (const float*)d_in[56], *bv_t1 = (const float*)d_in[57];
    const float *wq_t2 = (const float*)d_in[58], *bq_t2 = (const float*)d_in[59],
                *wk_t2 = (const float*)d_in[60], *bk_t2 = (const float*)d_in[61],
                *wv_t2 = (const float*)d_in[62], *bv_t2 = (const float*)d_in[63];
    const float *w_fa = (const float*)d_in[64], *b_fa = (const float*)d_in[65],
                *w_ft = (const float*)d_in[66], *b_ft = (const float*)d_in[67],
                *w_e  = (const float*)d_in[68], *b_e  = (const float*)d_in[69];

    float* ws = (float*)d_ws;
    const size_t Z0 = 0;                 // c2 -> c3 -> x4
    const size_t Z1 = 22091776ull;       // x1 -> p2 -> p3 -> GI
    const size_t OUTS  = 34072576ull;    // conv-wT (early) then GRU outputs
    const size_t AFEAT = 34712576ull;
    const size_t TFEAT = 34909184ull;
    const size_t XGAP  = 35105792ull;
    const size_t WT    = 35118080ull;
    float* X1 = ws + Z1;
    float* C2 = ws + Z0;  float* P2 = ws + Z1;
    float* C3 = ws + Z0;  float* P3 = ws + Z1;
    float* X4 = ws + Z0;  float* GI = ws + Z1;
    float* outs  = ws + OUTS;
    float* afeat = ws + AFEAT;
    float* tfeat = ws + TFEAT;
    float* xgap  = ws + XGAP;
    float* wqa1t = ws + WT;
    float* wka1t = wqa1t + 73728; float* wva1t = wka1t + 73728;
    float* wqa2t = wva1t + 73728; float* wka2t = wqa2t + 73728; float* wva2t = wka2t + 73728;
    // text transposed weights [n][c][o], 76800 floats each (layout used in R0-R2: fits ws)
    float* wqt1t = wva2t + 73728;
    float* wkt1t = wqt1t + 76800; float* wvt1t = wkt1t + 76800;
    float* wqt2t = wvt1t + 76800; float* wkt2t = wqt2t + 76800; float* wvt2t = wkt2t + 76800;
    // conv weight transposes parked in the (still dead) GRU outs region
    float* wT2 = outs;            //  6,912
    float* wT3 = outs + 6912;     // 18,432
    float* wT4 = outs + 25344;    // 55,296

    // ----- all weight transposes in ONE launch -----
    TPack tp;
    tp.d[0]  = {wq_a1, wqa1t, 96, 96, 73728};
    tp.d[1]  = {wk_a1, wka1t, 96, 96, 73728};
    tp.d[2]  = {wv_a1, wva1t, 96, 96, 73728};
    tp.d[3]  = {wq_a2, wqa2t, 96, 96, 73728};
    tp.d[4]  = {wk_a2, wka2t, 96, 96, 73728};
    tp.d[5]  = {wv_a2, wva2t, 96, 96, 73728};
    tp.d[6]  = {w2, wT2, 32, 216, 6912};
    tp.d[7]  = {w3, wT3, 64, 288, 18432};
    tp.d[8]  = {w4, wT4, 96, 576, 55296};
    tp.d[9]  = {wq_t1, wqt1t, 96, 100, 76800};
    tp.d[10] = {wk_t1, wkt1t, 96, 100, 76800};
    tp.d[11] = {wv_t1, wvt1t, 96, 100, 76800};
    tp.d[12] = {wq_t2, wqt2t, 96, 100, 76800};
    tp.d[13] = {wk_t2, wkt2t, 96, 100, 76800};
    tp.d[14] = {wv_t2, wvt2t, 96, 100, 76800};
    k_transpose_pack<<<dim3(300, 15), 256, 0, stream>>>(tp);

    // ----- fused stem (register-window conv taps) -----
    k_stem<<<46800, 256, 0, stream>>>(mfcc_t, mfcc_f, mfcc_c,
        w1a, b1a, g1a, be1a, m1a, v1a,
        w1b, b1b, g1b, be1b, m1b, v1b, X1, 11980800);
    k_conv3x3_tiled<24, 8, 25, 156, 9, 6><<<dim3(128, 3, 4), 256, 0, stream>>>(
        X1, wT2, b2, g2, be2, m2, v2, C2, 32);
    k_maxpool<<<14976, 256, 0, stream>>>(C2, P2, 32, 25, 156, 12, 78, 3833856);
    k_conv3x3_tiled<32, 8, 12, 78, 12, 4><<<dim3(128, 1, 8), 256, 0, stream>>>(
        P2, wT3, b3, g3, be3, m3, v3, C3, 64);
    k_maxpool<<<7488, 256, 0, stream>>>(C3, P3, 64, 12, 78, 6, 39, 1916928);
    k_conv3x3_tiled<64, 16, 6, 39, 6, 1><<<dim3(128, 1, 12), 256, 0, stream>>>(
        P3, wT4, b4, g4, be4, m4, v4, X4, 96);

    // ----- audio attention (+GAP folded in): exact R5 best -----
    k_audio_attn<<<dim3(kB, 8, 2), 128, 0, stream>>>(X4,
        wqa1t, bq_a1, wka1t, bk_a1, wva1t, bv_a1,
        wqa2t, bq_a2, wka2t, bk_a2, wva2t, bv_a2, afeat, xgap);

    // ----- text branch -----
    k_gi<<<kB * kT / 8, 320, 0, stream>>>(tokens, emb, w_ih, b_ih, GI);
    k_gru_all<<<kB, 320, 0, stream>>>(GI, w_hh, b_hh, outs);
    k_text_attn<<<dim3(kB, 2, 8), 128, 0, stream>>>(outs,
        wqt1t, bq_t1, wkt1t, bk_t1, wvt1t, bv_t1,
        wqt2t, bq_t2, wkt2t, bk_t2, wvt2t, bv_t2, tfeat);

    // ----- fusion + logits -----
    k_final<<<kB, 128, 0, stream>>>(xgap, outs, afeat, tfeat,
                                    w_fa, b_fa, w_ft, b_ft, w_e, b_e, (float*)d_out);
}